// Round 10
// baseline (1309.234 us; speedup 1.0000x reference)
//
#include <hip/hip_runtime.h>
#include <cmath>

#define MIN_NORM 1e-15f
#define RCPF(x)  __builtin_amdgcn_rcpf(x)
#define SQRTF(x) __builtin_amdgcn_sqrtf(x)
#define RSQF(x)  __builtin_amdgcn_rsqf(x)

template<int CTRL>
__device__ __forceinline__ float dpp_add(float v) {
    return __int_as_float(__builtin_amdgcn_update_dpp(0, __float_as_int(v), CTRL, 0xF, 0xF, false));
}

// butterfly sum within each 16-lane group
__device__ __forceinline__ float rsum16(float v) {
    v += dpp_add<0x121>(v);  // row_ror:1
    v += dpp_add<0x122>(v);  // row_ror:2
    v += dpp_add<0x124>(v);  // row_ror:4
    v += dpp_add<0x128>(v);  // row_ror:8
    return v;
}

// butterfly sum within each 8-lane group
__device__ __forceinline__ float rsum8(float v) {
    v += dpp_add<0xB1>(v);   // quad_perm xor1
    v += dpp_add<0x4E>(v);   // quad_perm xor2
    v += dpp_add<0x141>(v);  // row_half_mirror
    return v;
}

// tanh for x >= 0 via hardware exp
__device__ __forceinline__ float tanh_fast(float x) {
    float ex = __expf(fminf(2.f * x, 30.f));
    return (ex - 1.f) * RCPF(ex + 1.f);
}

// ---------------- edge sort by head (count/scan/scatter) ----------------
__global__ __launch_bounds__(256) void k_count(const int* __restrict__ head,
                                               int* __restrict__ C, int E) {
    int i = blockIdx.x * 256 + (int)threadIdx.x;
    if (i < E) atomicAdd(&C[head[i]], 1);
}

__global__ __launch_bounds__(256) void k_scan1(const int* __restrict__ C,
                                               int* __restrict__ T,
                                               int* __restrict__ BS, int N) {
    __shared__ int lds[256];
    int i = blockIdx.x * 256 + (int)threadIdx.x;
    int v = (i < N) ? C[i] : 0;
    lds[threadIdx.x] = v;
    __syncthreads();
    for (int off = 1; off < 256; off <<= 1) {
        int add = (threadIdx.x >= (unsigned)off) ? lds[threadIdx.x - off] : 0;
        __syncthreads();
        lds[threadIdx.x] += add;
        __syncthreads();
    }
    if (i < N) T[i] = lds[threadIdx.x];
    if (threadIdx.x == 255) BS[blockIdx.x] = lds[255];
}

__global__ __launch_bounds__(1024) void k_scan2(int* __restrict__ BS, int nb) {
    __shared__ int lds[1024];
    int v = ((int)threadIdx.x < nb) ? BS[threadIdx.x] : 0;
    lds[threadIdx.x] = v;
    __syncthreads();
    for (int off = 1; off < 1024; off <<= 1) {
        int add = (threadIdx.x >= (unsigned)off) ? lds[threadIdx.x - off] : 0;
        __syncthreads();
        lds[threadIdx.x] += add;
        __syncthreads();
    }
    if ((int)threadIdx.x < nb) BS[threadIdx.x] = lds[threadIdx.x] - v;  // exclusive
}

__global__ __launch_bounds__(256) void k_scan3(const int* __restrict__ C,
                                               const int* __restrict__ T,
                                               const int* __restrict__ BS,
                                               int* __restrict__ P, int N) {
    int i = blockIdx.x * 256 + (int)threadIdx.x;
    if (i < N) P[i] = T[i] - C[i] + BS[blockIdx.x];
}

// rec packs (tail, head | rtype<<20); head < 2^20, rtype < 32
__global__ __launch_bounds__(256) void k_scatter(const int* __restrict__ head,
                                                 const int* __restrict__ tail,
                                                 const int* __restrict__ etype,
                                                 int* __restrict__ P,
                                                 int2* __restrict__ rec, int E) {
    int i = blockIdx.x * 256 + (int)threadIdx.x;
    if (i < E) {
        int h = head[i];
        int pos = atomicAdd(&P[h], 1);
        rec[pos] = make_int2(tail[i], h | ((etype[i] - 1) << 20));
    }
}

// ---------------- tables ----------------
// hop-1: Th1={scp,p2} (head side), Tt1={nt,inv_nt} (tail side)
__global__ __launch_bounds__(256) void k_prep(const float4* __restrict__ src,
                                              float2* __restrict__ Th1,
                                              float2* __restrict__ Tt1, int N) {
    int gid = (blockIdx.x * 256 + (int)threadIdx.x) >> 4;
    int g   = (int)threadIdx.x & 15;
    if (gid >= N) return;
    float4 v = src[(size_t)gid * 16 + g];
    float n2 = rsum16(v.x * v.x + v.y * v.y + v.z * v.z + v.w * v.w);
    if (g == 0) {
        float nh     = fmaxf(SQRTF(fmaxf(n2, 0.f)), MIN_NORM);
        float inv_nh = RCPF(nh);
        float th     = tanh_fast(nh);
        Th1[gid] = make_float2(th * inv_nh, th * th);
        Tt1[gid] = make_float2(nh, inv_nh);
    }
}

// RelC1={nr,inv_nr} (hop-1), RelC2={scr2,y2r2} (hop-2, prefolded with ILAM2)
__global__ __launch_bounds__(256) void k_prep_rel(const float4* __restrict__ rel,
                                                  float2* __restrict__ RelC1,
                                                  float2* __restrict__ RelC2,
                                                  float ILAM2, int NR) {
    int gid = (blockIdx.x * 256 + (int)threadIdx.x) >> 4;
    int g   = (int)threadIdx.x & 15;
    if (gid >= NR) return;
    float4 v = rel[(size_t)gid * 16 + g];
    float n2 = rsum16(v.x * v.x + v.y * v.y + v.z * v.z + v.w * v.w);
    if (g == 0) {
        float nr = fmaxf(SQRTF(n2), MIN_NORM);
        float inv_nr = RCPF(nr);
        RelC1[gid] = make_float2(nr, inv_nr);
        float thr2 = tanh_fast(ILAM2 * nr);
        RelC2[gid] = make_float2(thr2 * inv_nr, thr2 * thr2);
    }
}

// ---- edge kernel: 8 lanes/edge, lane g owns dims {8g..8g+7} (float4 x2) ----
template<bool HOP2>
__global__ __launch_bounds__(256) void rgat_edge_kernel(
    const float*  __restrict__ e,      // [N,64]
    const float*  __restrict__ rel,    // [32,64]
    const float2* __restrict__ Th1,    // hop1: {scp,p2}
    const float2* __restrict__ Tt1,    // hop1: {nt,inv_nt}
    const float2* __restrict__ Tt2,    // hop2: {sct2,y2t2}
    const float2* __restrict__ RelC1,  // hop1: {nr,inv_nr}
    const float2* __restrict__ RelC2,  // hop2: {scr2,y2r2}
    const int2*   __restrict__ rec,    // [E] (tail, head|rtype<<20), head-sorted
    float*        __restrict__ sums,   // [N,64] pre-zeroed
    float SCP2, float P2C,             // hop2 head constants: tanh(1), tanh(1)^2
    int E)
{
    int tid = blockIdx.x * 256 + (int)threadIdx.x;
    int eid = tid >> 3;
    int g   = (int)threadIdx.x & 7;
    int s   = ((int)threadIdx.x >> 3) & 7;
    bool act = eid < E;
    int ec = act ? eid : (E - 1);

    int2 rc = rec[ec];
    int ti = rc.x;
    int hi = rc.y & 0xFFFFF;
    int ri = rc.y >> 20;

    const float* hrow = e   + (size_t)hi * 64 + g * 8;
    const float* trow = e   + (size_t)ti * 64 + g * 8;
    const float* urow = rel + (size_t)ri * 64 + g * 8;
    float4 ha = *(const float4*)(hrow);
    float4 hb = *(const float4*)(hrow + 4);
    float4 ta = *(const float4*)(trow);
    float4 tb = *(const float4*)(trow + 4);
    float4 ua = *(const float4*)(urow);
    float4 ub = *(const float4*)(urow + 4);

    // dots h.t, h.r, t.r
    float pht = ha.x*ta.x + ha.y*ta.y + ha.z*ta.z + ha.w*ta.w
              + hb.x*tb.x + hb.y*tb.y + hb.z*tb.z + hb.w*tb.w;
    float phr = ha.x*ua.x + ha.y*ua.y + ha.z*ua.z + ha.w*ua.w
              + hb.x*ub.x + hb.y*ub.y + hb.z*ub.z + hb.w*ub.w;
    float ptr_ = ta.x*ua.x + ta.y*ua.y + ta.z*ua.z + ta.w*ua.w
               + tb.x*ub.x + tb.y*ub.y + tb.z*ub.z + tb.w*ub.w;
    float ht  = rsum8(pht);
    float hr  = rsum8(phr);
    float ttr = rsum8(ptr_);

    // ---- per-edge scalars ----
    float scp, p2, sct, y2t, scr, y2r;
    if constexpr (HOP2) {
        scp = SCP2; p2 = P2C;
        float2 tv = Tt2[ti];   sct = tv.x; y2t = tv.y;
        float2 rv = RelC2[ri]; scr = rv.x; y2r = rv.y;
    } else {
        float2 hv = Th1[hi];   scp = hv.x; p2 = hv.y;
        float2 tv = Tt1[ti];
        float2 rv = RelC1[ri];
        float bet1  = fmaxf(1.f - p2, MIN_NORM);
        float ilam  = RCPF(bet1);
        float tht = tanh_fast(ilam * tv.x);
        sct = tht * tv.y;  y2t = tht * tht;
        float thr_ = tanh_fast(ilam * rv.x);
        scr = thr_ * rv.y; y2r = thr_ * thr_;
    }
    float bet = fmaxf(1.f - p2, MIN_NORM);

    float xyt = scp * sct * ht;
    float xyr = scp * scr * hr;

    float alt  = fmaf(2.f, xyt, 1.f + y2t);
    float dent = fmaxf(fmaf(p2, y2t, fmaf(2.f, xyt, 1.f)), MIN_NORM);
    float alr  = fmaf(2.f, xyr, 1.f + y2r);
    float denr = fmaxf(fmaf(p2, y2r, fmaf(2.f, xyr, 1.f)), MIN_NORM);
    float iS   = RCPF(dent * denr);
    float idt  = iS * denr;
    float idr  = iS * dent;

    float a2 = (alt * alt * p2 + 2.f * alt * bet * xyt + bet * bet * y2t) * idt * idt;
    float pa = fmaf(bet, xyt, alt * p2) * idt;
    float b2 = (alr * alr * p2 + 2.f * alr * bet * xyr + bet * bet * y2r) * idr * idr;
    float pb = fmaf(bet, xyr, alr * p2) * idr;

    float ytyr = sct * scr * ttr;
    float ab = (alt * alr * p2 + alt * bet * xyr + bet * alr * xyt + bet * bet * ytyr) * idt * idr;

    float am   = fmaf(2.f, ab, 1.f + b2);
    float bm   = 1.f - a2;
    float denm = fmaxf(fmaf(a2, b2, fmaf(2.f, ab, 1.f)), MIN_NORM);
    float idm  = RCPF(denm);
    float m2  = (am * am * a2 + 2.f * am * bm * ab + bm * bm * b2) * idm * idm;
    float pmv = fmaf(am, pa, bm * pb) * idm;

    // project via m2 compare
    const float maxn  = 1.f - 4e-3f;
    const float maxn2 = maxn * maxn;
    float irm = RSQF(fmaxf(m2, 1e-30f));
    float sc  = (m2 > maxn2) ? (maxn * irm) : 1.f;
    m2  *= sc * sc;
    pmv *= sc;

    // logmap scalars
    float cs   = fmaf(-2.f, pmv, 1.f + m2);
    float dens = fmaxf(fmaf(p2, m2, fmaf(-2.f, pmv, 1.f)), MIN_NORM);
    float ids  = RCPF(dens);
    float s2  = fmaxf((cs * cs * p2 - 2.f * cs * bet * pmv + bet * bet * m2) * ids * ids, 1e-30f);
    float irs = RSQF(s2);
    float ns  = s2 * irs;
    float xa  = fminf(ns, 1.f - 1e-7f);
    float ath = 0.5f * __logf((1.f + xa) * RCPF(1.f - xa));
    float lgs = bet * ath * irs;

    // collapse per-dim chain: res = relu(Kh*h + Kt*t + Kr*r)
    float X  = am * idt;
    float Y  = bm * idr;
    float G  = idm * sc;
    float W  = lgs * ids;
    float WG = W * G;
    float bet2 = bet * bet;
    float Kt = WG * X * bet2 * sct;
    float Kr = WG * Y * bet2 * scr;
    float Z  = WG * bet * fmaf(X, alt, Y * alr);
    float Kh = scp * (Z - W * cs);

    float amask = act ? 1.f : 0.f;
    float res[8];
    res[0] = fmaxf(fmaf(Kh, ha.x, fmaf(Kt, ta.x, Kr * ua.x)), 0.f) * amask;
    res[1] = fmaxf(fmaf(Kh, ha.y, fmaf(Kt, ta.y, Kr * ua.y)), 0.f) * amask;
    res[2] = fmaxf(fmaf(Kh, ha.z, fmaf(Kt, ta.z, Kr * ua.z)), 0.f) * amask;
    res[3] = fmaxf(fmaf(Kh, ha.w, fmaf(Kt, ta.w, Kr * ua.w)), 0.f) * amask;
    res[4] = fmaxf(fmaf(Kh, hb.x, fmaf(Kt, tb.x, Kr * ub.x)), 0.f) * amask;
    res[5] = fmaxf(fmaf(Kh, hb.y, fmaf(Kt, tb.y, Kr * ub.y)), 0.f) * amask;
    res[6] = fmaxf(fmaf(Kh, hb.z, fmaf(Kt, tb.z, Kr * ub.z)), 0.f) * amask;
    res[7] = fmaxf(fmaf(Kh, hb.w, fmaf(Kt, tb.w, Kr * ub.w)), 0.f) * amask;

    // --- segmented suffix-merge across the 8 sorted sub-edges ---
    int hn1 = __shfl_down(hi, 8, 64);
    int hn2 = __shfl_down(hi, 16, 64);
    int hn4 = __shfl_down(hi, 32, 64);
    int hp  = __shfl_up(hi, 8, 64);
    bool c1 = (s < 7) && (hn1 == hi);
    bool c2 = (s < 6) && (hn2 == hi);
    bool c4 = (s < 4) && (hn4 == hi);
    bool owner = (s == 0) || (hp != hi);
#pragma unroll
    for (int k = 0; k < 8; ++k) {
        float v1 = __shfl_down(res[k], 8, 64);
        res[k] += c1 ? v1 : 0.f;
    }
#pragma unroll
    for (int k = 0; k < 8; ++k) {
        float v2 = __shfl_down(res[k], 16, 64);
        res[k] += c2 ? v2 : 0.f;
    }
#pragma unroll
    for (int k = 0; k < 8; ++k) {
        float v4 = __shfl_down(res[k], 32, 64);
        res[k] += c4 ? v4 : 0.f;
    }

    if (owner) {
        float* dst = &sums[(size_t)hi * 64 + g * 8];
#pragma unroll
        for (int k = 0; k < 8; ++k) atomicAdd(dst + k, res[k]);
    }
}

// hop-1 epilogue: A = normalize(sums); zero sums; build hop-2 tail table Tt2
__global__ __launch_bounds__(256) void k_entity1(float4* __restrict__ sums,
                                                 float4* __restrict__ A,
                                                 float2* __restrict__ Tt2,
                                                 float ILAM2, int N) {
    int gid = (blockIdx.x * 256 + (int)threadIdx.x) >> 4;
    int g   = (int)threadIdx.x & 15;
    if (gid >= N) return;
    size_t idx = (size_t)gid * 16 + g;
    float4 sv = sums[idx];
    sums[idx] = make_float4(0.f, 0.f, 0.f, 0.f);   // zero for hop 2
    float n2 = rsum16(sv.x * sv.x + sv.y * sv.y + sv.z * sv.z + sv.w * sv.w);
    float inv = RCPF(fmaxf(SQRTF(n2), 1e-12f));
    float4 v = make_float4(sv.x * inv, sv.y * inv, sv.z * inv, sv.w * inv);
    A[idx] = v;
    if (g == 0) {
        // norm of normalized row: 1 for nonzero rows, 0 for zero rows
        float nv = SQRTF(n2) * inv;
        float nt = fmaxf(nv, MIN_NORM);
        float tht2 = tanh_fast(ILAM2 * nt);
        Tt2[gid] = make_float2(tht2 * RCPF(nt), tht2 * tht2);
    }
}

// hop-2 epilogue (in place on d_out): out = 0.25*ent + 0.5*e1n + normalize(sums2)
__global__ __launch_bounds__(256) void k_entity2(float4* __restrict__ out,
                                                 const float4* __restrict__ ent,
                                                 const float4* __restrict__ A, int N) {
    int gid = (blockIdx.x * 256 + (int)threadIdx.x) >> 4;
    int g   = (int)threadIdx.x & 15;
    if (gid >= N) return;
    size_t idx = (size_t)gid * 16 + g;
    float4 sv = out[idx];
    float n2 = rsum16(sv.x * sv.x + sv.y * sv.y + sv.z * sv.z + sv.w * sv.w);
    float inv = RCPF(fmaxf(SQRTF(n2), 1e-12f));
    float4 en = ent[idx];
    float4 a  = A[idx];
    float4 o;
    o.x = fmaf(0.25f, en.x, fmaf(0.5f, a.x, sv.x * inv));
    o.y = fmaf(0.25f, en.y, fmaf(0.5f, a.y, sv.y * inv));
    o.z = fmaf(0.25f, en.z, fmaf(0.5f, a.z, sv.z * inv));
    o.w = fmaf(0.25f, en.w, fmaf(0.5f, a.w, sv.w * inv));
    out[idx] = o;
}

extern "C" void kernel_launch(void* const* d_in, const int* in_sizes, int n_in,
                              void* d_out, int out_size, void* d_ws, size_t ws_size,
                              hipStream_t stream)
{
    const float* ent   = (const float*)d_in[0];   // [N,64]
    const float* rel   = (const float*)d_in[1];   // [32,64]
    const int*   eidx  = (const int*)d_in[2];     // [2,E]
    const int*   etype = (const int*)d_in[3];     // [E]

    int E = in_sizes[3];
    int N = in_sizes[0] / 64;
    int NR = in_sizes[1] / 64;
    const int* head = eidx;
    const int* tail = eidx + E;

    // hop-2 head-side constants (all rows unit-norm after l2_normalize)
    double th1d = tanh(1.0);
    float SCP2  = (float)th1d;
    float P2C   = (float)(th1d * th1d);
    float ILAM2 = (float)(1.0 / (1.0 - th1d * th1d));

    // ws: A[N*64 f32] | rec[E int2] | Th1,Tt1,Tt2[N f2] | RelC1,RelC2[NR f2] | P,C,Tsc[N int] | BS
    float*  A     = (float*)d_ws;                      // 51.2 MB
    int2*   rec   = (int2*)(A + (size_t)N * 64);       // 8 MB
    float2* Th1   = (float2*)(rec + E);                // 1.6 MB each
    float2* Tt1   = Th1 + N;
    float2* Tt2   = Tt1 + N;
    float2* RelC1 = Tt2 + N;
    float2* RelC2 = RelC1 + NR;
    int*    P     = (int*)(RelC2 + NR);
    int*    C     = P + N;
    int*    Tsc   = C + N;
    int*    BS    = Tsc + N;                           // <=1024 ints

    int NB = (N + 255) / 256;       // 782 (<=1024)
    int EB = (E + 255) / 256;

    float* out = (float*)d_out;
    size_t embBytes = (size_t)N * 64 * sizeof(float);

    dim3 blk(256);
    int prepGrid = (N * 16 + 255) / 256;
    int relGrid  = (NR * 16 + 255) / 256;
    int edgeGrid = (E * 8 + 255) / 256;   // 8 lanes per edge

    // sort edges by head (reused by both hops)
    (void)hipMemsetAsync(C, 0, (size_t)N * sizeof(int), stream);
    k_count  <<<EB, blk, 0, stream>>>(head, C, E);
    k_scan1  <<<NB, blk, 0, stream>>>(C, Tsc, BS, N);
    k_scan2  <<<1, 1024, 0, stream>>>(BS, NB);
    k_scan3  <<<NB, blk, 0, stream>>>(C, Tsc, BS, P, N);
    k_scatter<<<EB, blk, 0, stream>>>(head, tail, etype, P, rec, E);

    // tables
    k_prep    <<<prepGrid, blk, 0, stream>>>((const float4*)ent, Th1, Tt1, N);
    k_prep_rel<<<relGrid,  blk, 0, stream>>>((const float4*)rel, RelC1, RelC2, ILAM2, NR);

    // hop 1
    (void)hipMemsetAsync(out, 0, embBytes, stream);
    rgat_edge_kernel<false><<<edgeGrid, blk, 0, stream>>>(
        ent, rel, Th1, Tt1, Tt2, RelC1, RelC2, rec, out, SCP2, P2C, E);
    k_entity1<<<prepGrid, blk, 0, stream>>>((float4*)out, (float4*)A, Tt2, ILAM2, N);

    // hop 2
    rgat_edge_kernel<true><<<edgeGrid, blk, 0, stream>>>(
        A, rel, Th1, Tt1, Tt2, RelC1, RelC2, rec, out, SCP2, P2C, E);
    k_entity2<<<prepGrid, blk, 0, stream>>>((float4*)out, (const float4*)ent, (const float4*)A, N);
}

// Round 11
// 448.464 us; speedup vs baseline: 2.9194x; 2.9194x over previous
//
#include <hip/hip_runtime.h>
#include <cmath>

#define MIN_NORM 1e-15f
#define RCPF(x)  __builtin_amdgcn_rcpf(x)
#define SQRTF(x) __builtin_amdgcn_sqrtf(x)
#define RSQF(x)  __builtin_amdgcn_rsqf(x)

template<int CTRL>
__device__ __forceinline__ float dpp_add(float v) {
    return __int_as_float(__builtin_amdgcn_update_dpp(0, __float_as_int(v), CTRL, 0xF, 0xF, false));
}

// butterfly sum within each 16-lane group
__device__ __forceinline__ float rsum16(float v) {
    v += dpp_add<0x121>(v);  // row_ror:1
    v += dpp_add<0x122>(v);  // row_ror:2
    v += dpp_add<0x124>(v);  // row_ror:4
    v += dpp_add<0x128>(v);  // row_ror:8
    return v;
}

// butterfly sum within each 8-lane group
__device__ __forceinline__ float rsum8(float v) {
    v += dpp_add<0xB1>(v);   // quad_perm xor1
    v += dpp_add<0x4E>(v);   // quad_perm xor2
    v += dpp_add<0x141>(v);  // row_half_mirror
    return v;
}

// tanh for x >= 0 via hardware exp
__device__ __forceinline__ float tanh_fast(float x) {
    float ex = __expf(fminf(2.f * x, 30.f));
    return (ex - 1.f) * RCPF(ex + 1.f);
}

// ---------------- edge sort by head (count/scan/scatter) ----------------
__global__ __launch_bounds__(256) void k_count(const int* __restrict__ head,
                                               int* __restrict__ C, int E) {
    int i = blockIdx.x * 256 + (int)threadIdx.x;
    if (i < E) atomicAdd(&C[head[i]], 1);
}

__global__ __launch_bounds__(256) void k_scan1(const int* __restrict__ C,
                                               int* __restrict__ T,
                                               int* __restrict__ BS, int N) {
    __shared__ int lds[256];
    int i = blockIdx.x * 256 + (int)threadIdx.x;
    int v = (i < N) ? C[i] : 0;
    lds[threadIdx.x] = v;
    __syncthreads();
    for (int off = 1; off < 256; off <<= 1) {
        int add = (threadIdx.x >= (unsigned)off) ? lds[threadIdx.x - off] : 0;
        __syncthreads();
        lds[threadIdx.x] += add;
        __syncthreads();
    }
    if (i < N) T[i] = lds[threadIdx.x];
    if (threadIdx.x == 255) BS[blockIdx.x] = lds[255];
}

__global__ __launch_bounds__(1024) void k_scan2(int* __restrict__ BS, int nb) {
    __shared__ int lds[1024];
    int v = ((int)threadIdx.x < nb) ? BS[threadIdx.x] : 0;
    lds[threadIdx.x] = v;
    __syncthreads();
    for (int off = 1; off < 1024; off <<= 1) {
        int add = (threadIdx.x >= (unsigned)off) ? lds[threadIdx.x - off] : 0;
        __syncthreads();
        lds[threadIdx.x] += add;
        __syncthreads();
    }
    if ((int)threadIdx.x < nb) BS[threadIdx.x] = lds[threadIdx.x] - v;  // exclusive
}

__global__ __launch_bounds__(256) void k_scan3(const int* __restrict__ C,
                                               const int* __restrict__ T,
                                               const int* __restrict__ BS,
                                               int* __restrict__ P, int N) {
    int i = blockIdx.x * 256 + (int)threadIdx.x;
    if (i < N) P[i] = T[i] - C[i] + BS[blockIdx.x];
}

// rec packs (tail, head | rtype<<20); head < 2^20, rtype < 32
__global__ __launch_bounds__(256) void k_scatter(const int* __restrict__ head,
                                                 const int* __restrict__ tail,
                                                 const int* __restrict__ etype,
                                                 int* __restrict__ P,
                                                 int2* __restrict__ rec, int E) {
    int i = blockIdx.x * 256 + (int)threadIdx.x;
    if (i < E) {
        int h = head[i];
        int pos = atomicAdd(&P[h], 1);
        rec[pos] = make_int2(tail[i], h | ((etype[i] - 1) << 20));
    }
}

// ---------------- tables ----------------
__global__ __launch_bounds__(256) void k_prep(const float4* __restrict__ src,
                                              float2* __restrict__ Th1,
                                              float2* __restrict__ Tt1, int N) {
    int gid = (blockIdx.x * 256 + (int)threadIdx.x) >> 4;
    int g   = (int)threadIdx.x & 15;
    if (gid >= N) return;
    float4 v = src[(size_t)gid * 16 + g];
    float n2 = rsum16(v.x * v.x + v.y * v.y + v.z * v.z + v.w * v.w);
    if (g == 0) {
        float nh     = fmaxf(SQRTF(fmaxf(n2, 0.f)), MIN_NORM);
        float inv_nh = RCPF(nh);
        float th     = tanh_fast(nh);
        Th1[gid] = make_float2(th * inv_nh, th * th);
        Tt1[gid] = make_float2(nh, inv_nh);
    }
}

__global__ __launch_bounds__(256) void k_prep_rel(const float4* __restrict__ rel,
                                                  float2* __restrict__ RelC1,
                                                  float2* __restrict__ RelC2,
                                                  float ILAM2, int NR) {
    int gid = (blockIdx.x * 256 + (int)threadIdx.x) >> 4;
    int g   = (int)threadIdx.x & 15;
    if (gid >= NR) return;
    float4 v = rel[(size_t)gid * 16 + g];
    float n2 = rsum16(v.x * v.x + v.y * v.y + v.z * v.z + v.w * v.w);
    if (g == 0) {
        float nr = fmaxf(SQRTF(n2), MIN_NORM);
        float inv_nr = RCPF(nr);
        RelC1[gid] = make_float2(nr, inv_nr);
        float thr2 = tanh_fast(ILAM2 * nr);
        RelC2[gid] = make_float2(thr2 * inv_nr, thr2 * thr2);
    }
}

// ---- edge kernel: 8 lanes/edge; contiguous loads {8g..8g+7}; LDS-transpose
//      before scatter so each atomic instruction writes 8 consecutive dwords ----
template<bool HOP2>
__global__ __launch_bounds__(256) void rgat_edge_kernel(
    const float*  __restrict__ e,      // [N,64]
    const float*  __restrict__ rel,    // [32,64]
    const float2* __restrict__ Th1,    // hop1: {scp,p2}
    const float2* __restrict__ Tt1,    // hop1: {nt,inv_nt}
    const float2* __restrict__ Tt2,    // hop2: {sct2,y2t2}
    const float2* __restrict__ RelC1,  // hop1: {nr,inv_nr}
    const float2* __restrict__ RelC2,  // hop2: {scr2,y2r2}
    const int2*   __restrict__ rec,    // [E] (tail, head|rtype<<20), head-sorted
    float*        __restrict__ sums,   // [N,64] pre-zeroed
    float SCP2, float P2C,             // hop2 head constants
    int E)
{
    __shared__ float xp[4][8][72];     // per-wave 8x64 tile, rows padded to 72

    int tid = blockIdx.x * 256 + (int)threadIdx.x;
    int eid = tid >> 3;
    int g   = (int)threadIdx.x & 7;
    int s   = ((int)threadIdx.x >> 3) & 7;
    int w   = (int)threadIdx.x >> 6;
    bool act = eid < E;
    int ec = act ? eid : (E - 1);

    int2 rc = rec[ec];
    int ti = rc.x;
    int hi = rc.y & 0xFFFFF;
    int ri = rc.y >> 20;

    const float* hrow = e   + (size_t)hi * 64 + g * 8;
    const float* trow = e   + (size_t)ti * 64 + g * 8;
    const float* urow = rel + (size_t)ri * 64 + g * 8;
    float4 ha = *(const float4*)(hrow);
    float4 hb = *(const float4*)(hrow + 4);
    float4 ta = *(const float4*)(trow);
    float4 tb = *(const float4*)(trow + 4);
    float4 ua = *(const float4*)(urow);
    float4 ub = *(const float4*)(urow + 4);

    float pht = ha.x*ta.x + ha.y*ta.y + ha.z*ta.z + ha.w*ta.w
              + hb.x*tb.x + hb.y*tb.y + hb.z*tb.z + hb.w*tb.w;
    float phr = ha.x*ua.x + ha.y*ua.y + ha.z*ua.z + ha.w*ua.w
              + hb.x*ub.x + hb.y*ub.y + hb.z*ub.z + hb.w*ub.w;
    float ptr_ = ta.x*ua.x + ta.y*ua.y + ta.z*ua.z + ta.w*ua.w
               + tb.x*ub.x + tb.y*ub.y + tb.z*ub.z + tb.w*ub.w;
    float ht  = rsum8(pht);
    float hr  = rsum8(phr);
    float ttr = rsum8(ptr_);

    // ---- per-edge scalars ----
    float scp, p2, sct, y2t, scr, y2r;
    if constexpr (HOP2) {
        scp = SCP2; p2 = P2C;
        float2 tv = Tt2[ti];   sct = tv.x; y2t = tv.y;
        float2 rv = RelC2[ri]; scr = rv.x; y2r = rv.y;
    } else {
        float2 hv = Th1[hi];   scp = hv.x; p2 = hv.y;
        float2 tv = Tt1[ti];
        float2 rv = RelC1[ri];
        float bet1  = fmaxf(1.f - p2, MIN_NORM);
        float ilam  = RCPF(bet1);
        float tht = tanh_fast(ilam * tv.x);
        sct = tht * tv.y;  y2t = tht * tht;
        float thr_ = tanh_fast(ilam * rv.x);
        scr = thr_ * rv.y; y2r = thr_ * thr_;
    }
    float bet = fmaxf(1.f - p2, MIN_NORM);

    float xyt = scp * sct * ht;
    float xyr = scp * scr * hr;

    float alt  = fmaf(2.f, xyt, 1.f + y2t);
    float dent = fmaxf(fmaf(p2, y2t, fmaf(2.f, xyt, 1.f)), MIN_NORM);
    float alr  = fmaf(2.f, xyr, 1.f + y2r);
    float denr = fmaxf(fmaf(p2, y2r, fmaf(2.f, xyr, 1.f)), MIN_NORM);
    float iS   = RCPF(dent * denr);
    float idt  = iS * denr;
    float idr  = iS * dent;

    float a2 = (alt * alt * p2 + 2.f * alt * bet * xyt + bet * bet * y2t) * idt * idt;
    float pa = fmaf(bet, xyt, alt * p2) * idt;
    float b2 = (alr * alr * p2 + 2.f * alr * bet * xyr + bet * bet * y2r) * idr * idr;
    float pb = fmaf(bet, xyr, alr * p2) * idr;

    float ytyr = sct * scr * ttr;
    float ab = (alt * alr * p2 + alt * bet * xyr + bet * alr * xyt + bet * bet * ytyr) * idt * idr;

    float am   = fmaf(2.f, ab, 1.f + b2);
    float bm   = 1.f - a2;
    float denm = fmaxf(fmaf(a2, b2, fmaf(2.f, ab, 1.f)), MIN_NORM);
    float idm  = RCPF(denm);
    float m2  = (am * am * a2 + 2.f * am * bm * ab + bm * bm * b2) * idm * idm;
    float pmv = fmaf(am, pa, bm * pb) * idm;

    const float maxn  = 1.f - 4e-3f;
    const float maxn2 = maxn * maxn;
    float irm = RSQF(fmaxf(m2, 1e-30f));
    float sc  = (m2 > maxn2) ? (maxn * irm) : 1.f;
    m2  *= sc * sc;
    pmv *= sc;

    float cs   = fmaf(-2.f, pmv, 1.f + m2);
    float dens = fmaxf(fmaf(p2, m2, fmaf(-2.f, pmv, 1.f)), MIN_NORM);
    float ids  = RCPF(dens);
    float s2  = fmaxf((cs * cs * p2 - 2.f * cs * bet * pmv + bet * bet * m2) * ids * ids, 1e-30f);
    float irs = RSQF(s2);
    float ns  = s2 * irs;
    float xa  = fminf(ns, 1.f - 1e-7f);
    float ath = 0.5f * __logf((1.f + xa) * RCPF(1.f - xa));
    float lgs = bet * ath * irs;

    // collapse per-dim chain: res = relu(Kh*h + Kt*t + Kr*r)
    float X  = am * idt;
    float Y  = bm * idr;
    float G  = idm * sc;
    float W  = lgs * ids;
    float WG = W * G;
    float bet2 = bet * bet;
    float Kt = WG * X * bet2 * sct;
    float Kr = WG * Y * bet2 * scr;
    float Z  = WG * bet * fmaf(X, alt, Y * alr);
    float Kh = scp * (Z - W * cs);

    float amask = act ? 1.f : 0.f;
    float res[8];
    res[0] = fmaxf(fmaf(Kh, ha.x, fmaf(Kt, ta.x, Kr * ua.x)), 0.f) * amask;
    res[1] = fmaxf(fmaf(Kh, ha.y, fmaf(Kt, ta.y, Kr * ua.y)), 0.f) * amask;
    res[2] = fmaxf(fmaf(Kh, ha.z, fmaf(Kt, ta.z, Kr * ua.z)), 0.f) * amask;
    res[3] = fmaxf(fmaf(Kh, ha.w, fmaf(Kt, ta.w, Kr * ua.w)), 0.f) * amask;
    res[4] = fmaxf(fmaf(Kh, hb.x, fmaf(Kt, tb.x, Kr * ub.x)), 0.f) * amask;
    res[5] = fmaxf(fmaf(Kh, hb.y, fmaf(Kt, tb.y, Kr * ub.y)), 0.f) * amask;
    res[6] = fmaxf(fmaf(Kh, hb.z, fmaf(Kt, tb.z, Kr * ub.z)), 0.f) * amask;
    res[7] = fmaxf(fmaf(Kh, hb.w, fmaf(Kt, tb.w, Kr * ub.w)), 0.f) * amask;

    // --- segmented suffix-merge across the 8 sorted sub-edges (per slot) ---
    int hn1 = __shfl_down(hi, 8, 64);
    int hn2 = __shfl_down(hi, 16, 64);
    int hn4 = __shfl_down(hi, 32, 64);
    int hp  = __shfl_up(hi, 8, 64);
    bool c1 = (s < 7) && (hn1 == hi);
    bool c2 = (s < 6) && (hn2 == hi);
    bool c4 = (s < 4) && (hn4 == hi);
    bool owner = (s == 0) || (hp != hi);
#pragma unroll
    for (int k = 0; k < 8; ++k) {
        float v1 = __shfl_down(res[k], 8, 64);
        res[k] += c1 ? v1 : 0.f;
    }
#pragma unroll
    for (int k = 0; k < 8; ++k) {
        float v2 = __shfl_down(res[k], 16, 64);
        res[k] += c2 ? v2 : 0.f;
    }
#pragma unroll
    for (int k = 0; k < 8; ++k) {
        float v4 = __shfl_down(res[k], 32, 64);
        res[k] += c4 ? v4 : 0.f;
    }

    // --- 8x8 transpose via LDS: lane g ends up holding dims {g+8k} ---
#pragma unroll
    for (int k = 0; k < 8; ++k) xp[w][s][g * 8 + k] = res[k];
    __syncthreads();
    float rest[8];
#pragma unroll
    for (int k = 0; k < 8; ++k) rest[k] = xp[w][s][g + 8 * k];

    if (owner) {
        float* dst = &sums[(size_t)hi * 64 + g];
#pragma unroll
        for (int k = 0; k < 8; ++k) atomicAdd(dst + 8 * k, rest[k]);
    }
}

// hop-1 epilogue: A = normalize(sums); zero sums; build hop-2 tail table Tt2
__global__ __launch_bounds__(256) void k_entity1(float4* __restrict__ sums,
                                                 float4* __restrict__ A,
                                                 float2* __restrict__ Tt2,
                                                 float ILAM2, int N) {
    int gid = (blockIdx.x * 256 + (int)threadIdx.x) >> 4;
    int g   = (int)threadIdx.x & 15;
    if (gid >= N) return;
    size_t idx = (size_t)gid * 16 + g;
    float4 sv = sums[idx];
    sums[idx] = make_float4(0.f, 0.f, 0.f, 0.f);   // zero for hop 2
    float n2 = rsum16(sv.x * sv.x + sv.y * sv.y + sv.z * sv.z + sv.w * sv.w);
    float inv = RCPF(fmaxf(SQRTF(n2), 1e-12f));
    float4 v = make_float4(sv.x * inv, sv.y * inv, sv.z * inv, sv.w * inv);
    A[idx] = v;
    if (g == 0) {
        float nv = SQRTF(n2) * inv;            // 1 for nonzero rows, ~0 for zero rows
        float nt = fmaxf(nv, MIN_NORM);
        float tht2 = tanh_fast(ILAM2 * nt);
        Tt2[gid] = make_float2(tht2 * RCPF(nt), tht2 * tht2);
    }
}

// hop-2 epilogue (in place on d_out): out = 0.25*ent + 0.5*e1n + normalize(sums2)
__global__ __launch_bounds__(256) void k_entity2(float4* __restrict__ out,
                                                 const float4* __restrict__ ent,
                                                 const float4* __restrict__ A, int N) {
    int gid = (blockIdx.x * 256 + (int)threadIdx.x) >> 4;
    int g   = (int)threadIdx.x & 15;
    if (gid >= N) return;
    size_t idx = (size_t)gid * 16 + g;
    float4 sv = out[idx];
    float n2 = rsum16(sv.x * sv.x + sv.y * sv.y + sv.z * sv.z + sv.w * sv.w);
    float inv = RCPF(fmaxf(SQRTF(n2), 1e-12f));
    float4 en = ent[idx];
    float4 a  = A[idx];
    float4 o;
    o.x = fmaf(0.25f, en.x, fmaf(0.5f, a.x, sv.x * inv));
    o.y = fmaf(0.25f, en.y, fmaf(0.5f, a.y, sv.y * inv));
    o.z = fmaf(0.25f, en.z, fmaf(0.5f, a.z, sv.z * inv));
    o.w = fmaf(0.25f, en.w, fmaf(0.5f, a.w, sv.w * inv));
    out[idx] = o;
}

extern "C" void kernel_launch(void* const* d_in, const int* in_sizes, int n_in,
                              void* d_out, int out_size, void* d_ws, size_t ws_size,
                              hipStream_t stream)
{
    const float* ent   = (const float*)d_in[0];   // [N,64]
    const float* rel   = (const float*)d_in[1];   // [32,64]
    const int*   eidx  = (const int*)d_in[2];     // [2,E]
    const int*   etype = (const int*)d_in[3];     // [E]

    int E = in_sizes[3];
    int N = in_sizes[0] / 64;
    int NR = in_sizes[1] / 64;
    const int* head = eidx;
    const int* tail = eidx + E;

    double th1d = tanh(1.0);
    float SCP2  = (float)th1d;
    float P2C   = (float)(th1d * th1d);
    float ILAM2 = (float)(1.0 / (1.0 - th1d * th1d));

    float*  A     = (float*)d_ws;                      // 51.2 MB
    int2*   rec   = (int2*)(A + (size_t)N * 64);       // 8 MB
    float2* Th1   = (float2*)(rec + E);
    float2* Tt1   = Th1 + N;
    float2* Tt2   = Tt1 + N;
    float2* RelC1 = Tt2 + N;
    float2* RelC2 = RelC1 + NR;
    int*    P     = (int*)(RelC2 + NR);
    int*    C     = P + N;
    int*    Tsc   = C + N;
    int*    BS    = Tsc + N;

    int NB = (N + 255) / 256;       // 782 (<=1024)
    int EB = (E + 255) / 256;

    float* out = (float*)d_out;
    size_t embBytes = (size_t)N * 64 * sizeof(float);

    dim3 blk(256);
    int prepGrid = (N * 16 + 255) / 256;
    int relGrid  = (NR * 16 + 255) / 256;
    int edgeGrid = (E * 8 + 255) / 256;

    (void)hipMemsetAsync(C, 0, (size_t)N * sizeof(int), stream);
    k_count  <<<EB, blk, 0, stream>>>(head, C, E);
    k_scan1  <<<NB, blk, 0, stream>>>(C, Tsc, BS, N);
    k_scan2  <<<1, 1024, 0, stream>>>(BS, NB);
    k_scan3  <<<NB, blk, 0, stream>>>(C, Tsc, BS, P, N);
    k_scatter<<<EB, blk, 0, stream>>>(head, tail, etype, P, rec, E);

    k_prep    <<<prepGrid, blk, 0, stream>>>((const float4*)ent, Th1, Tt1, N);
    k_prep_rel<<<relGrid,  blk, 0, stream>>>((const float4*)rel, RelC1, RelC2, ILAM2, NR);

    (void)hipMemsetAsync(out, 0, embBytes, stream);
    rgat_edge_kernel<false><<<edgeGrid, blk, 0, stream>>>(
        ent, rel, Th1, Tt1, Tt2, RelC1, RelC2, rec, out, SCP2, P2C, E);
    k_entity1<<<prepGrid, blk, 0, stream>>>((float4*)out, (float4*)A, Tt2, ILAM2, N);

    rgat_edge_kernel<true><<<edgeGrid, blk, 0, stream>>>(
        A, rel, Th1, Tt1, Tt2, RelC1, RelC2, rec, out, SCP2, P2C, E);
    k_entity2<<<prepGrid, blk, 0, stream>>>((float4*)out, (const float4*)ent, (const float4*)A, N);
}

// Round 12
// 445.653 us; speedup vs baseline: 2.9378x; 1.0063x over previous
//
#include <hip/hip_runtime.h>
#include <cmath>

#define MIN_NORM 1e-15f
#define RCPF(x)  __builtin_amdgcn_rcpf(x)
#define SQRTF(x) __builtin_amdgcn_sqrtf(x)
#define RSQF(x)  __builtin_amdgcn_rsqf(x)

template<int CTRL>
__device__ __forceinline__ float dpp_add(float v) {
    return __int_as_float(__builtin_amdgcn_update_dpp(0, __float_as_int(v), CTRL, 0xF, 0xF, false));
}

__device__ __forceinline__ float rsum16(float v) {
    v += dpp_add<0x121>(v);
    v += dpp_add<0x122>(v);
    v += dpp_add<0x124>(v);
    v += dpp_add<0x128>(v);
    return v;
}

__device__ __forceinline__ float rsum8(float v) {
    v += dpp_add<0xB1>(v);   // quad_perm xor1
    v += dpp_add<0x4E>(v);   // quad_perm xor2
    v += dpp_add<0x141>(v);  // row_half_mirror
    return v;
}

__device__ __forceinline__ float tanh_fast(float x) {
    float ex = __expf(fminf(2.f * x, 30.f));
    return (ex - 1.f) * RCPF(ex + 1.f);
}

// ---------------- edge sort by head ----------------
__global__ __launch_bounds__(256) void k_count(const int* __restrict__ head,
                                               int* __restrict__ C, int E) {
    int i = blockIdx.x * 256 + (int)threadIdx.x;
    if (i < E) atomicAdd(&C[head[i]], 1);
}

__global__ __launch_bounds__(256) void k_scan1(const int* __restrict__ C,
                                               int* __restrict__ T,
                                               int* __restrict__ BS, int N) {
    __shared__ int lds[256];
    int i = blockIdx.x * 256 + (int)threadIdx.x;
    int v = (i < N) ? C[i] : 0;
    lds[threadIdx.x] = v;
    __syncthreads();
    for (int off = 1; off < 256; off <<= 1) {
        int add = (threadIdx.x >= (unsigned)off) ? lds[threadIdx.x - off] : 0;
        __syncthreads();
        lds[threadIdx.x] += add;
        __syncthreads();
    }
    if (i < N) T[i] = lds[threadIdx.x];
    if (threadIdx.x == 255) BS[blockIdx.x] = lds[255];
}

__global__ __launch_bounds__(1024) void k_scan2(int* __restrict__ BS, int nb) {
    __shared__ int lds[1024];
    int v = ((int)threadIdx.x < nb) ? BS[threadIdx.x] : 0;
    lds[threadIdx.x] = v;
    __syncthreads();
    for (int off = 1; off < 1024; off <<= 1) {
        int add = (threadIdx.x >= (unsigned)off) ? lds[threadIdx.x - off] : 0;
        __syncthreads();
        lds[threadIdx.x] += add;
        __syncthreads();
    }
    if ((int)threadIdx.x < nb) BS[threadIdx.x] = lds[threadIdx.x] - v;
}

__global__ __launch_bounds__(256) void k_scan3(const int* __restrict__ C,
                                               const int* __restrict__ T,
                                               const int* __restrict__ BS,
                                               int* __restrict__ P, int N) {
    int i = blockIdx.x * 256 + (int)threadIdx.x;
    if (i < N) P[i] = T[i] - C[i] + BS[blockIdx.x];
}

__global__ __launch_bounds__(256) void k_scatter(const int* __restrict__ head,
                                                 const int* __restrict__ tail,
                                                 const int* __restrict__ etype,
                                                 int* __restrict__ P,
                                                 int2* __restrict__ rec, int E) {
    int i = blockIdx.x * 256 + (int)threadIdx.x;
    if (i < E) {
        int h = head[i];
        int pos = atomicAdd(&P[h], 1);
        rec[pos] = make_int2(tail[i], h | ((etype[i] - 1) << 20));
    }
}

// ---------------- tables ----------------
__global__ __launch_bounds__(256) void k_prep(const float4* __restrict__ src,
                                              float2* __restrict__ Th1,
                                              float2* __restrict__ Tt1, int N) {
    int gid = (blockIdx.x * 256 + (int)threadIdx.x) >> 4;
    int g   = (int)threadIdx.x & 15;
    if (gid >= N) return;
    float4 v = src[(size_t)gid * 16 + g];
    float n2 = rsum16(v.x * v.x + v.y * v.y + v.z * v.z + v.w * v.w);
    if (g == 0) {
        float nh     = fmaxf(SQRTF(fmaxf(n2, 0.f)), MIN_NORM);
        float inv_nh = RCPF(nh);
        float th     = tanh_fast(nh);
        Th1[gid] = make_float2(th * inv_nh, th * th);
        Tt1[gid] = make_float2(nh, inv_nh);
    }
}

__global__ __launch_bounds__(256) void k_prep_rel(const float4* __restrict__ rel,
                                                  float2* __restrict__ RelC1,
                                                  float2* __restrict__ RelC2,
                                                  float ILAM2, int NR) {
    int gid = (blockIdx.x * 256 + (int)threadIdx.x) >> 4;
    int g   = (int)threadIdx.x & 15;
    if (gid >= NR) return;
    float4 v = rel[(size_t)gid * 16 + g];
    float n2 = rsum16(v.x * v.x + v.y * v.y + v.z * v.z + v.w * v.w);
    if (g == 0) {
        float nr = fmaxf(SQRTF(n2), MIN_NORM);
        float inv_nr = RCPF(nr);
        RelC1[gid] = make_float2(nr, inv_nr);
        float thr2 = tanh_fast(ILAM2 * nr);
        RelC2[gid] = make_float2(thr2 * inv_nr, thr2 * thr2);
    }
}

// ---- per-group compute: 8 sorted edges, 8 lanes each; lane g owns dims {g+8k} ----
template<bool HOP2>
__device__ __forceinline__ void proc_group(
    int hi, bool act, int s, int g,
    const float* h, const float* t, const float* r,
    float2 hv, float2 tv, float2 rv,
    float SCP2, float P2C,
    float* __restrict__ sums)
{
    float pht = 0.f, phr = 0.f, ptr_ = 0.f;
#pragma unroll
    for (int k = 0; k < 8; ++k) {
        pht  += h[k] * t[k];
        phr  += h[k] * r[k];
        ptr_ += t[k] * r[k];
    }
    float ht  = rsum8(pht);
    float hr  = rsum8(phr);
    float ttr = rsum8(ptr_);

    float scp, p2, sct, y2t, scr, y2r;
    if constexpr (HOP2) {
        scp = SCP2; p2 = P2C;
        sct = tv.x; y2t = tv.y;
        scr = rv.x; y2r = rv.y;
    } else {
        scp = hv.x; p2 = hv.y;
        float bet1 = fmaxf(1.f - p2, MIN_NORM);
        float ilam = RCPF(bet1);
        float tht = tanh_fast(ilam * tv.x);
        sct = tht * tv.y;  y2t = tht * tht;
        float thr_ = tanh_fast(ilam * rv.x);
        scr = thr_ * rv.y; y2r = thr_ * thr_;
    }
    float bet = fmaxf(1.f - p2, MIN_NORM);

    float xyt = scp * sct * ht;
    float xyr = scp * scr * hr;

    float alt  = fmaf(2.f, xyt, 1.f + y2t);
    float dent = fmaxf(fmaf(p2, y2t, fmaf(2.f, xyt, 1.f)), MIN_NORM);
    float alr  = fmaf(2.f, xyr, 1.f + y2r);
    float denr = fmaxf(fmaf(p2, y2r, fmaf(2.f, xyr, 1.f)), MIN_NORM);
    float iS   = RCPF(dent * denr);
    float idt  = iS * denr;
    float idr  = iS * dent;

    float a2 = (alt * alt * p2 + 2.f * alt * bet * xyt + bet * bet * y2t) * idt * idt;
    float pa = fmaf(bet, xyt, alt * p2) * idt;
    float b2 = (alr * alr * p2 + 2.f * alr * bet * xyr + bet * bet * y2r) * idr * idr;
    float pb = fmaf(bet, xyr, alr * p2) * idr;

    float ytyr = sct * scr * ttr;
    float ab = (alt * alr * p2 + alt * bet * xyr + bet * alr * xyt + bet * bet * ytyr) * idt * idr;

    float am   = fmaf(2.f, ab, 1.f + b2);
    float bm   = 1.f - a2;
    float denm = fmaxf(fmaf(a2, b2, fmaf(2.f, ab, 1.f)), MIN_NORM);
    float idm  = RCPF(denm);
    float m2  = (am * am * a2 + 2.f * am * bm * ab + bm * bm * b2) * idm * idm;
    float pmv = fmaf(am, pa, bm * pb) * idm;

    const float maxn  = 1.f - 4e-3f;
    const float maxn2 = maxn * maxn;
    float irm = RSQF(fmaxf(m2, 1e-30f));
    float sc  = (m2 > maxn2) ? (maxn * irm) : 1.f;
    m2  *= sc * sc;
    pmv *= sc;

    float cs   = fmaf(-2.f, pmv, 1.f + m2);
    float dens = fmaxf(fmaf(p2, m2, fmaf(-2.f, pmv, 1.f)), MIN_NORM);
    float ids  = RCPF(dens);
    float s2  = fmaxf((cs * cs * p2 - 2.f * cs * bet * pmv + bet * bet * m2) * ids * ids, 1e-30f);
    float irs = RSQF(s2);
    float ns  = s2 * irs;
    float xa  = fminf(ns, 1.f - 1e-7f);
    float ath = 0.5f * __logf((1.f + xa) * RCPF(1.f - xa));
    float lgs = bet * ath * irs;

    float X  = am * idt;
    float Y  = bm * idr;
    float G  = idm * sc;
    float W  = lgs * ids;
    float WG = W * G;
    float bet2 = bet * bet;
    float Kt = WG * X * bet2 * sct;
    float Kr = WG * Y * bet2 * scr;
    float Z  = WG * bet * fmaf(X, alt, Y * alr);
    float Kh = scp * (Z - W * cs);

    float amask = act ? 1.f : 0.f;
    float res[8];
#pragma unroll
    for (int k = 0; k < 8; ++k)
        res[k] = fmaxf(fmaf(Kh, h[k], fmaf(Kt, t[k], Kr * r[k])), 0.f) * amask;

    // segmented suffix-merge across 8 sorted sub-edges
    int hn1 = __shfl_down(hi, 8, 64);
    int hn2 = __shfl_down(hi, 16, 64);
    int hn4 = __shfl_down(hi, 32, 64);
    int hp  = __shfl_up(hi, 8, 64);
    bool c1 = (s < 7) && (hn1 == hi);
    bool c2 = (s < 6) && (hn2 == hi);
    bool c4 = (s < 4) && (hn4 == hi);
    bool owner = (s == 0) || (hp != hi);
#pragma unroll
    for (int k = 0; k < 8; ++k) {
        float v1 = __shfl_down(res[k], 8, 64);
        res[k] += c1 ? v1 : 0.f;
    }
#pragma unroll
    for (int k = 0; k < 8; ++k) {
        float v2 = __shfl_down(res[k], 16, 64);
        res[k] += c2 ? v2 : 0.f;
    }
#pragma unroll
    for (int k = 0; k < 8; ++k) {
        float v4 = __shfl_down(res[k], 32, 64);
        res[k] += c4 ? v4 : 0.f;
    }

    if (owner) {
        float* dst = &sums[(size_t)hi * 64 + g];
#pragma unroll
        for (int k = 0; k < 8; ++k) atomicAdd(dst + 8 * k, res[k]);
    }
}

// ---- edge kernel: 32 edges/wave (4 groups of 8), 2-deep software pipeline ----
template<bool HOP2>
__global__ __launch_bounds__(256) void rgat_edge_kernel(
    const float*  __restrict__ e,
    const float*  __restrict__ rel,
    const float2* __restrict__ Th1,
    const float2* __restrict__ Tt1,
    const float2* __restrict__ Tt2,
    const float2* __restrict__ RelC1,
    const float2* __restrict__ RelC2,
    const int2*   __restrict__ rec,
    float*        __restrict__ sums,
    float SCP2, float P2C,
    int E)
{
    int tid  = blockIdx.x * 256 + (int)threadIdx.x;
    int wave = tid >> 6;
    int lane = (int)threadIdx.x & 63;
    int g = lane & 7;
    int s = lane >> 3;
    int base = wave * 32;
    if (base >= E) return;

    // preload + decode all 4 group records (independent loads, issued up front)
    int hiA[4], tiA[4], riA[4];
    bool actA[4];
#pragma unroll
    for (int j = 0; j < 4; ++j) {
        int eid = base + j * 8 + s;
        actA[j] = eid < E;
        int ec = actA[j] ? eid : (E - 1);
        int2 rc = rec[ec];
        tiA[j] = rc.x;
        hiA[j] = rc.y & 0xFFFFF;
        riA[j] = rc.y >> 20;
    }

    auto LOAD = [&](int j, float* H, float* T, float* R,
                    float2& HV, float2& TV, float2& RV) {
        const float* hrow = e   + (size_t)hiA[j] * 64 + g;
        const float* trow = e   + (size_t)tiA[j] * 64 + g;
        const float* rrow = rel + (size_t)riA[j] * 64 + g;
#pragma unroll
        for (int k = 0; k < 8; ++k) {
            H[k] = hrow[8 * k];
            T[k] = trow[8 * k];
            R[k] = rrow[8 * k];
        }
        if constexpr (HOP2) {
            TV = Tt2[tiA[j]];
            RV = RelC2[riA[j]];
            HV = make_float2(0.f, 0.f);
        } else {
            HV = Th1[hiA[j]];
            TV = Tt1[tiA[j]];
            RV = RelC1[riA[j]];
        }
    };

    float hA[8], tA[8], rA[8], hB[8], tB[8], rB[8];
    float2 hvA, tvA, rvA, hvB, tvB, rvB;

    LOAD(0, hA, tA, rA, hvA, tvA, rvA);
    LOAD(1, hB, tB, rB, hvB, tvB, rvB);
    proc_group<HOP2>(hiA[0], actA[0], s, g, hA, tA, rA, hvA, tvA, rvA, SCP2, P2C, sums);
    LOAD(2, hA, tA, rA, hvA, tvA, rvA);
    proc_group<HOP2>(hiA[1], actA[1], s, g, hB, tB, rB, hvB, tvB, rvB, SCP2, P2C, sums);
    LOAD(3, hB, tB, rB, hvB, tvB, rvB);
    proc_group<HOP2>(hiA[2], actA[2], s, g, hA, tA, rA, hvA, tvA, rvA, SCP2, P2C, sums);
    proc_group<HOP2>(hiA[3], actA[3], s, g, hB, tB, rB, hvB, tvB, rvB, SCP2, P2C, sums);
}

// hop-1 epilogue
__global__ __launch_bounds__(256) void k_entity1(float4* __restrict__ sums,
                                                 float4* __restrict__ A,
                                                 float2* __restrict__ Tt2,
                                                 float ILAM2, int N) {
    int gid = (blockIdx.x * 256 + (int)threadIdx.x) >> 4;
    int g   = (int)threadIdx.x & 15;
    if (gid >= N) return;
    size_t idx = (size_t)gid * 16 + g;
    float4 sv = sums[idx];
    sums[idx] = make_float4(0.f, 0.f, 0.f, 0.f);
    float n2 = rsum16(sv.x * sv.x + sv.y * sv.y + sv.z * sv.z + sv.w * sv.w);
    float inv = RCPF(fmaxf(SQRTF(n2), 1e-12f));
    float4 v = make_float4(sv.x * inv, sv.y * inv, sv.z * inv, sv.w * inv);
    A[idx] = v;
    if (g == 0) {
        float nv = SQRTF(n2) * inv;
        float nt = fmaxf(nv, MIN_NORM);
        float tht2 = tanh_fast(ILAM2 * nt);
        Tt2[gid] = make_float2(tht2 * RCPF(nt), tht2 * tht2);
    }
}

// hop-2 epilogue
__global__ __launch_bounds__(256) void k_entity2(float4* __restrict__ out,
                                                 const float4* __restrict__ ent,
                                                 const float4* __restrict__ A, int N) {
    int gid = (blockIdx.x * 256 + (int)threadIdx.x) >> 4;
    int g   = (int)threadIdx.x & 15;
    if (gid >= N) return;
    size_t idx = (size_t)gid * 16 + g;
    float4 sv = out[idx];
    float n2 = rsum16(sv.x * sv.x + sv.y * sv.y + sv.z * sv.z + sv.w * sv.w);
    float inv = RCPF(fmaxf(SQRTF(n2), 1e-12f));
    float4 en = ent[idx];
    float4 a  = A[idx];
    float4 o;
    o.x = fmaf(0.25f, en.x, fmaf(0.5f, a.x, sv.x * inv));
    o.y = fmaf(0.25f, en.y, fmaf(0.5f, a.y, sv.y * inv));
    o.z = fmaf(0.25f, en.z, fmaf(0.5f, a.z, sv.z * inv));
    o.w = fmaf(0.25f, en.w, fmaf(0.5f, a.w, sv.w * inv));
    out[idx] = o;
}

extern "C" void kernel_launch(void* const* d_in, const int* in_sizes, int n_in,
                              void* d_out, int out_size, void* d_ws, size_t ws_size,
                              hipStream_t stream)
{
    const float* ent   = (const float*)d_in[0];
    const float* rel   = (const float*)d_in[1];
    const int*   eidx  = (const int*)d_in[2];
    const int*   etype = (const int*)d_in[3];

    int E = in_sizes[3];
    int N = in_sizes[0] / 64;
    int NR = in_sizes[1] / 64;
    const int* head = eidx;
    const int* tail = eidx + E;

    double th1d = tanh(1.0);
    float SCP2  = (float)th1d;
    float P2C   = (float)(th1d * th1d);
    float ILAM2 = (float)(1.0 / (1.0 - th1d * th1d));

    float*  A     = (float*)d_ws;
    int2*   rec   = (int2*)(A + (size_t)N * 64);
    float2* Th1   = (float2*)(rec + E);
    float2* Tt1   = Th1 + N;
    float2* Tt2   = Tt1 + N;
    float2* RelC1 = Tt2 + N;
    float2* RelC2 = RelC1 + NR;
    int*    P     = (int*)(RelC2 + NR);
    int*    C     = P + N;
    int*    Tsc   = C + N;
    int*    BS    = Tsc + N;

    int NB = (N + 255) / 256;
    int EB = (E + 255) / 256;

    float* out = (float*)d_out;
    size_t embBytes = (size_t)N * 64 * sizeof(float);

    dim3 blk(256);
    int prepGrid = (N * 16 + 255) / 256;
    int relGrid  = (NR * 16 + 255) / 256;
    int edgeGrid = (E + 127) / 128;   // 32 edges/wave, 4 waves/block

    (void)hipMemsetAsync(C, 0, (size_t)N * sizeof(int), stream);
    k_count  <<<EB, blk, 0, stream>>>(head, C, E);
    k_scan1  <<<NB, blk, 0, stream>>>(C, Tsc, BS, N);
    k_scan2  <<<1, 1024, 0, stream>>>(BS, NB);
    k_scan3  <<<NB, blk, 0, stream>>>(C, Tsc, BS, P, N);
    k_scatter<<<EB, blk, 0, stream>>>(head, tail, etype, P, rec, E);

    k_prep    <<<prepGrid, blk, 0, stream>>>((const float4*)ent, Th1, Tt1, N);
    k_prep_rel<<<relGrid,  blk, 0, stream>>>((const float4*)rel, RelC1, RelC2, ILAM2, NR);

    (void)hipMemsetAsync(out, 0, embBytes, stream);
    rgat_edge_kernel<false><<<edgeGrid, blk, 0, stream>>>(
        ent, rel, Th1, Tt1, Tt2, RelC1, RelC2, rec, out, SCP2, P2C, E);
    k_entity1<<<prepGrid, blk, 0, stream>>>((float4*)out, (float4*)A, Tt2, ILAM2, N);

    rgat_edge_kernel<true><<<edgeGrid, blk, 0, stream>>>(
        A, rel, Th1, Tt1, Tt2, RelC1, RelC2, rec, out, SCP2, P2C, E);
    k_entity2<<<prepGrid, blk, 0, stream>>>((float4*)out, (const float4*)ent, (const float4*)A, N);
}

// Round 13
// 382.446 us; speedup vs baseline: 3.4233x; 1.1653x over previous
//
#include <hip/hip_runtime.h>
#include <cmath>

#define MIN_NORM 1e-15f
#define RCPF(x)  __builtin_amdgcn_rcpf(x)
#define SQRTF(x) __builtin_amdgcn_sqrtf(x)
#define RSQF(x)  __builtin_amdgcn_rsqf(x)

template<int CTRL>
__device__ __forceinline__ float dpp_add(float v) {
    return __int_as_float(__builtin_amdgcn_update_dpp(0, __float_as_int(v), CTRL, 0xF, 0xF, false));
}

__device__ __forceinline__ float rsum16(float v) {
    v += dpp_add<0x121>(v);
    v += dpp_add<0x122>(v);
    v += dpp_add<0x124>(v);
    v += dpp_add<0x128>(v);
    return v;
}

// butterfly sum across each adjacent-8-lane group
__device__ __forceinline__ float rsum8(float v) {
    v += dpp_add<0xB1>(v);   // quad_perm xor1
    v += dpp_add<0x4E>(v);   // quad_perm xor2
    v += dpp_add<0x141>(v);  // row_half_mirror
    return v;
}

__device__ __forceinline__ float tanh_fast(float x) {
    float ex = __expf(fminf(2.f * x, 30.f));
    return (ex - 1.f) * RCPF(ex + 1.f);
}

// ---------------- CSR build (count/scan/scatter) ----------------
__global__ __launch_bounds__(256) void k_count(const int* __restrict__ head,
                                               int* __restrict__ C, int E) {
    int i = blockIdx.x * 256 + (int)threadIdx.x;
    if (i < E) atomicAdd(&C[head[i]], 1);
}

__global__ __launch_bounds__(256) void k_scan1(const int* __restrict__ C,
                                               int* __restrict__ T,
                                               int* __restrict__ BS, int N) {
    __shared__ int lds[256];
    int i = blockIdx.x * 256 + (int)threadIdx.x;
    int v = (i < N) ? C[i] : 0;
    lds[threadIdx.x] = v;
    __syncthreads();
    for (int off = 1; off < 256; off <<= 1) {
        int add = (threadIdx.x >= (unsigned)off) ? lds[threadIdx.x - off] : 0;
        __syncthreads();
        lds[threadIdx.x] += add;
        __syncthreads();
    }
    if (i < N) T[i] = lds[threadIdx.x];
    if (threadIdx.x == 255) BS[blockIdx.x] = lds[255];
}

__global__ __launch_bounds__(1024) void k_scan2(int* __restrict__ BS, int nb) {
    __shared__ int lds[1024];
    int v = ((int)threadIdx.x < nb) ? BS[threadIdx.x] : 0;
    lds[threadIdx.x] = v;
    __syncthreads();
    for (int off = 1; off < 1024; off <<= 1) {
        int add = (threadIdx.x >= (unsigned)off) ? lds[threadIdx.x - off] : 0;
        __syncthreads();
        lds[threadIdx.x] += add;
        __syncthreads();
    }
    if ((int)threadIdx.x < nb) BS[threadIdx.x] = lds[threadIdx.x] - v;
}

// O = exclusive offsets (+O[N]=E), P = cursor copy
__global__ __launch_bounds__(256) void k_scan3(const int* __restrict__ C,
                                               const int* __restrict__ T,
                                               const int* __restrict__ BS,
                                               int* __restrict__ O,
                                               int* __restrict__ P, int N, int E) {
    int i = blockIdx.x * 256 + (int)threadIdx.x;
    if (i < N) {
        int o = T[i] - C[i] + BS[blockIdx.x];
        O[i] = o;
        P[i] = o;
    }
    if (i == 0) O[N] = E;
}

// rec packs tail | rtype<<20 (tail < 2^20, rtype < 32)
__global__ __launch_bounds__(256) void k_scatter(const int* __restrict__ head,
                                                 const int* __restrict__ tail,
                                                 const int* __restrict__ etype,
                                                 int* __restrict__ P,
                                                 int* __restrict__ rec, int E) {
    int i = blockIdx.x * 256 + (int)threadIdx.x;
    if (i < E) {
        int pos = atomicAdd(&P[head[i]], 1);
        rec[pos] = tail[i] | ((etype[i] - 1) << 20);
    }
}

// ---------------- degree-bucket sort of heads ----------------
__global__ __launch_bounds__(256) void k_dhist(const int* __restrict__ O,
                                               int* __restrict__ DH, int N) {
    __shared__ int lh[64];
    if (threadIdx.x < 64) lh[threadIdx.x] = 0;
    __syncthreads();
    int i = blockIdx.x * 256 + (int)threadIdx.x;
    if (i < N) {
        int d = min(O[i + 1] - O[i], 63);
        atomicAdd(&lh[d], 1);
    }
    __syncthreads();
    if (threadIdx.x < 64 && lh[threadIdx.x] > 0)
        atomicAdd(&DH[threadIdx.x], lh[threadIdx.x]);
}

// exclusive scan of DH[64] -> DB (cursors)
__global__ __launch_bounds__(64) void k_dscan(const int* __restrict__ DH,
                                              int* __restrict__ DB) {
    __shared__ int lds[64];
    int t = (int)threadIdx.x;
    int v = DH[t];
    lds[t] = v;
    __syncthreads();
    for (int off = 1; off < 64; off <<= 1) {
        int add = (t >= off) ? lds[t - off] : 0;
        __syncthreads();
        lds[t] += add;
        __syncthreads();
    }
    DB[t] = lds[t] - v;   // exclusive
}

__global__ __launch_bounds__(256) void k_dscatter(const int* __restrict__ O,
                                                  int* __restrict__ DB,
                                                  int* __restrict__ perm, int N) {
    __shared__ int lh[64];
    __shared__ int lbase[64];
    if (threadIdx.x < 64) lh[threadIdx.x] = 0;
    __syncthreads();
    int i = blockIdx.x * 256 + (int)threadIdx.x;
    int d = -1, lr = 0;
    if (i < N) {
        d = min(O[i + 1] - O[i], 63);
        lr = atomicAdd(&lh[d], 1);
    }
    __syncthreads();
    if (threadIdx.x < 64 && lh[threadIdx.x] > 0)
        lbase[threadIdx.x] = atomicAdd(&DB[threadIdx.x], lh[threadIdx.x]);
    __syncthreads();
    if (d >= 0) perm[lbase[d] + lr] = i;
}

// ---------------- tables ----------------
__global__ __launch_bounds__(256) void k_prep(const float4* __restrict__ src,
                                              float2* __restrict__ Th1,
                                              float2* __restrict__ Tt1, int N) {
    int gid = (blockIdx.x * 256 + (int)threadIdx.x) >> 4;
    int g   = (int)threadIdx.x & 15;
    if (gid >= N) return;
    float4 v = src[(size_t)gid * 16 + g];
    float n2 = rsum16(v.x * v.x + v.y * v.y + v.z * v.z + v.w * v.w);
    if (g == 0) {
        float nh     = fmaxf(SQRTF(fmaxf(n2, 0.f)), MIN_NORM);
        float inv_nh = RCPF(nh);
        float th     = tanh_fast(nh);
        Th1[gid] = make_float2(th * inv_nh, th * th);
        Tt1[gid] = make_float2(nh, inv_nh);
    }
}

__global__ __launch_bounds__(256) void k_prep_rel(const float4* __restrict__ rel,
                                                  float2* __restrict__ RelC1,
                                                  float2* __restrict__ RelC2,
                                                  float ILAM2, int NR) {
    int gid = (blockIdx.x * 256 + (int)threadIdx.x) >> 4;
    int g   = (int)threadIdx.x & 15;
    if (gid >= NR) return;
    float4 v = rel[(size_t)gid * 16 + g];
    float n2 = rsum16(v.x * v.x + v.y * v.y + v.z * v.z + v.w * v.w);
    if (g == 0) {
        float nr = fmaxf(SQRTF(n2), MIN_NORM);
        float inv_nr = RCPF(nr);
        RelC1[gid] = make_float2(nr, inv_nr);
        float thr2 = tanh_fast(ILAM2 * nr);
        RelC2[gid] = make_float2(thr2 * inv_nr, thr2 * thr2);
    }
}

// ---- hop kernel: one 8-lane group per head; serial CSR run; plain stores ----
// lane = q*8 + l: q = head slot (0..7), l owns dims {l + 8k}, k=0..7
template<bool HOP2>
__global__ __launch_bounds__(256) void rgat_hop_kernel(
    const float*  __restrict__ e,
    const float*  __restrict__ rel,
    const float2* __restrict__ Th1,
    const float2* __restrict__ Tt1,
    const float2* __restrict__ Tt2,
    const float2* __restrict__ RelC1,
    const float2* __restrict__ RelC2,
    const int*    __restrict__ rec,    // tail | rtype<<20, head-sorted
    const int*    __restrict__ O,      // [N+1]
    const int*    __restrict__ perm,   // [N] degree-sorted head ids
    float*        __restrict__ sums,   // [N,64] fully written
    float SCP2, float P2C, int N)
{
    int tid  = blockIdx.x * 256 + (int)threadIdx.x;
    int slot = tid >> 3;               // global head slot
    int l    = (int)threadIdx.x & 7;
    bool act = slot < N;
    int h    = perm[act ? slot : 0];

    int beg = act ? O[h] : 0;
    int end = act ? O[h + 1] : 0;

    // head row + head-side scalars (once per head)
    const float* hrow = e + (size_t)h * 64 + l;
    float hv[8];
#pragma unroll
    for (int k = 0; k < 8; ++k) hv[k] = hrow[8 * k];

    float scp, p2;
    if constexpr (HOP2) {
        scp = SCP2; p2 = P2C;
    } else {
        float2 th = Th1[h];
        scp = th.x; p2 = th.y;
    }
    float bet  = fmaxf(1.f - p2, MIN_NORM);
    float ilam = RCPF(bet);
    float bet2 = bet * bet;

    float acc[8];
#pragma unroll
    for (int k = 0; k < 8; ++k) acc[k] = 0.f;

    float tA[8], rA[8], tB[8], rB[8];
    float2 tvA, rvA, tvB, rvB;

    auto LD = [&](int i, float* T, float* R, float2& TV, float2& RV) {
        int rc = rec[i];
        int ti = rc & 0xFFFFF;
        int ri = rc >> 20;
        const float* tr = e   + (size_t)ti * 64 + l;
        const float* rr = rel + (size_t)ri * 64 + l;
#pragma unroll
        for (int k = 0; k < 8; ++k) { T[k] = tr[8 * k]; R[k] = rr[8 * k]; }
        if constexpr (HOP2) { TV = Tt2[ti]; RV = RelC2[ri]; }
        else               { TV = Tt1[ti]; RV = RelC1[ri]; }
    };

    auto COMPUTE = [&](const float* t, const float* r, float2 tv, float2 rv) {
        float pht = 0.f, phr = 0.f, ptr_ = 0.f;
#pragma unroll
        for (int k = 0; k < 8; ++k) {
            pht  += hv[k] * t[k];
            phr  += hv[k] * r[k];
            ptr_ += t[k] * r[k];
        }
        float ht  = rsum8(pht);
        float hr  = rsum8(phr);
        float ttr = rsum8(ptr_);

        float sct, y2t, scr, y2r;
        if constexpr (HOP2) {
            sct = tv.x; y2t = tv.y;
            scr = rv.x; y2r = rv.y;
        } else {
            float tht = tanh_fast(ilam * tv.x);
            sct = tht * tv.y;  y2t = tht * tht;
            float thr_ = tanh_fast(ilam * rv.x);
            scr = thr_ * rv.y; y2r = thr_ * thr_;
        }

        float xyt = scp * sct * ht;
        float xyr = scp * scr * hr;

        float alt  = fmaf(2.f, xyt, 1.f + y2t);
        float dent = fmaxf(fmaf(p2, y2t, fmaf(2.f, xyt, 1.f)), MIN_NORM);
        float alr  = fmaf(2.f, xyr, 1.f + y2r);
        float denr = fmaxf(fmaf(p2, y2r, fmaf(2.f, xyr, 1.f)), MIN_NORM);
        float iS   = RCPF(dent * denr);
        float idt  = iS * denr;
        float idr  = iS * dent;

        float a2 = (alt * alt * p2 + 2.f * alt * bet * xyt + bet * bet * y2t) * idt * idt;
        float pa = fmaf(bet, xyt, alt * p2) * idt;
        float b2 = (alr * alr * p2 + 2.f * alr * bet * xyr + bet * bet * y2r) * idr * idr;
        float pb = fmaf(bet, xyr, alr * p2) * idr;

        float ytyr = sct * scr * ttr;
        float ab = (alt * alr * p2 + alt * bet * xyr + bet * alr * xyt + bet * bet * ytyr) * idt * idr;

        float am   = fmaf(2.f, ab, 1.f + b2);
        float bm   = 1.f - a2;
        float denm = fmaxf(fmaf(a2, b2, fmaf(2.f, ab, 1.f)), MIN_NORM);
        float idm  = RCPF(denm);
        float m2  = (am * am * a2 + 2.f * am * bm * ab + bm * bm * b2) * idm * idm;
        float pmv = fmaf(am, pa, bm * pb) * idm;

        const float maxn  = 1.f - 4e-3f;
        const float maxn2 = maxn * maxn;
        float irm = RSQF(fmaxf(m2, 1e-30f));
        float sc  = (m2 > maxn2) ? (maxn * irm) : 1.f;
        m2  *= sc * sc;
        pmv *= sc;

        float cs   = fmaf(-2.f, pmv, 1.f + m2);
        float dens = fmaxf(fmaf(p2, m2, fmaf(-2.f, pmv, 1.f)), MIN_NORM);
        float ids  = RCPF(dens);
        float s2  = fmaxf((cs * cs * p2 - 2.f * cs * bet * pmv + bet * bet * m2) * ids * ids, 1e-30f);
        float irs = RSQF(s2);
        float ns  = s2 * irs;
        float xa  = fminf(ns, 1.f - 1e-7f);
        float ath = 0.5f * __logf((1.f + xa) * RCPF(1.f - xa));
        float lgs = bet * ath * irs;

        float X  = am * idt;
        float Y  = bm * idr;
        float G  = idm * sc;
        float W  = lgs * ids;
        float WG = W * G;
        float Kt = WG * X * bet2 * sct;
        float Kr = WG * Y * bet2 * scr;
        float Z  = WG * bet * fmaf(X, alt, Y * alr);
        float Kh = scp * (Z - W * cs);

#pragma unroll
        for (int k = 0; k < 8; ++k)
            acc[k] += fmaxf(fmaf(Kh, hv[k], fmaf(Kt, t[k], Kr * r[k])), 0.f);
    };

    // 2-stage pipelined run over this head's edges
    int i = beg;
    if (i < end) {
        LD(i, tA, rA, tvA, rvA);
        while (true) {
            if (i + 1 < end) LD(i + 1, tB, rB, tvB, rvB);
            COMPUTE(tA, rA, tvA, rvA);
            ++i;
            if (i >= end) break;
            if (i + 1 < end) LD(i + 1, tA, rA, tvA, rvA);
            COMPUTE(tB, rB, tvB, rvB);
            ++i;
            if (i >= end) break;
        }
    }

    if (act) {
        float* dst = &sums[(size_t)h * 64 + l];
#pragma unroll
        for (int k = 0; k < 8; ++k) dst[8 * k] = acc[k];
    }
}

// hop-1 epilogue: A = normalize(sums); build hop-2 tail table Tt2 (no zeroing)
__global__ __launch_bounds__(256) void k_entity1(const float4* __restrict__ sums,
                                                 float4* __restrict__ A,
                                                 float2* __restrict__ Tt2,
                                                 float ILAM2, int N) {
    int gid = (blockIdx.x * 256 + (int)threadIdx.x) >> 4;
    int g   = (int)threadIdx.x & 15;
    if (gid >= N) return;
    size_t idx = (size_t)gid * 16 + g;
    float4 sv = sums[idx];
    float n2 = rsum16(sv.x * sv.x + sv.y * sv.y + sv.z * sv.z + sv.w * sv.w);
    float inv = RCPF(fmaxf(SQRTF(n2), 1e-12f));
    float4 v = make_float4(sv.x * inv, sv.y * inv, sv.z * inv, sv.w * inv);
    A[idx] = v;
    if (g == 0) {
        float nv = SQRTF(n2) * inv;            // 1 for nonzero rows, ~0 for zero rows
        float nt = fmaxf(nv, MIN_NORM);
        float tht2 = tanh_fast(ILAM2 * nt);
        Tt2[gid] = make_float2(tht2 * RCPF(nt), tht2 * tht2);
    }
}

// hop-2 epilogue (in place on d_out): out = 0.25*ent + 0.5*e1n + normalize(sums2)
__global__ __launch_bounds__(256) void k_entity2(float4* __restrict__ out,
                                                 const float4* __restrict__ ent,
                                                 const float4* __restrict__ A, int N) {
    int gid = (blockIdx.x * 256 + (int)threadIdx.x) >> 4;
    int g   = (int)threadIdx.x & 15;
    if (gid >= N) return;
    size_t idx = (size_t)gid * 16 + g;
    float4 sv = out[idx];
    float n2 = rsum16(sv.x * sv.x + sv.y * sv.y + sv.z * sv.z + sv.w * sv.w);
    float inv = RCPF(fmaxf(SQRTF(n2), 1e-12f));
    float4 en = ent[idx];
    float4 a  = A[idx];
    float4 o;
    o.x = fmaf(0.25f, en.x, fmaf(0.5f, a.x, sv.x * inv));
    o.y = fmaf(0.25f, en.y, fmaf(0.5f, a.y, sv.y * inv));
    o.z = fmaf(0.25f, en.z, fmaf(0.5f, a.z, sv.z * inv));
    o.w = fmaf(0.25f, en.w, fmaf(0.5f, a.w, sv.w * inv));
    out[idx] = o;
}

extern "C" void kernel_launch(void* const* d_in, const int* in_sizes, int n_in,
                              void* d_out, int out_size, void* d_ws, size_t ws_size,
                              hipStream_t stream)
{
    const float* ent   = (const float*)d_in[0];
    const float* rel   = (const float*)d_in[1];
    const int*   eidx  = (const int*)d_in[2];
    const int*   etype = (const int*)d_in[3];

    int E = in_sizes[3];
    int N = in_sizes[0] / 64;
    int NR = in_sizes[1] / 64;
    const int* head = eidx;
    const int* tail = eidx + E;

    double th1d = tanh(1.0);
    float SCP2  = (float)th1d;
    float P2C   = (float)(th1d * th1d);
    float ILAM2 = (float)(1.0 / (1.0 - th1d * th1d));

    // ws: A[N*64] | rec[E] | O[N+1] | P,C,Tsc,perm[N] | Th1,Tt1,Tt2[N f2] | RelC | DH,DB | BS
    float*  A     = (float*)d_ws;                      // 51.2 MB
    int*    rec   = (int*)(A + (size_t)N * 64);        // 4 MB
    int*    O     = rec + E;                           // N+1
    int*    P     = O + (N + 1);
    int*    C     = P + N;
    int*    Tsc   = C + N;
    int*    perm  = Tsc + N;
    float2* Th1   = (float2*)(perm + N);
    float2* Tt1   = Th1 + N;
    float2* Tt2   = Tt1 + N;
    float2* RelC1 = Tt2 + N;
    float2* RelC2 = RelC1 + NR;
    int*    DH    = (int*)(RelC2 + NR);                // 64
    int*    DB    = DH + 64;                           // 64
    int*    BS    = DB + 64;                           // <=1024

    int NB = (N + 255) / 256;
    int EB = (E + 255) / 256;

    float* out = (float*)d_out;

    dim3 blk(256);
    int prepGrid = (N * 16 + 255) / 256;
    int relGrid  = (NR * 16 + 255) / 256;
    int hopGrid  = (N * 8 + 255) / 256;    // 8 lanes per head

    // CSR build
    (void)hipMemsetAsync(C, 0, (size_t)N * sizeof(int), stream);
    k_count  <<<EB, blk, 0, stream>>>(head, C, E);
    k_scan1  <<<NB, blk, 0, stream>>>(C, Tsc, BS, N);
    k_scan2  <<<1, 1024, 0, stream>>>(BS, NB);
    k_scan3  <<<NB, blk, 0, stream>>>(C, Tsc, BS, O, P, N, E);
    k_scatter<<<EB, blk, 0, stream>>>(head, tail, etype, P, rec, E);

    // degree-sorted head permutation
    (void)hipMemsetAsync(DH, 0, 128 * sizeof(int), stream);
    k_dhist   <<<NB, blk, 0, stream>>>(O, DH, N);
    k_dscan   <<<1, 64, 0, stream>>>(DH, DB);
    k_dscatter<<<NB, blk, 0, stream>>>(O, DB, perm, N);

    // tables
    k_prep    <<<prepGrid, blk, 0, stream>>>((const float4*)ent, Th1, Tt1, N);
    k_prep_rel<<<relGrid,  blk, 0, stream>>>((const float4*)rel, RelC1, RelC2, ILAM2, NR);

    // hop 1: full-row stores into d_out (no memset), then normalize -> A + Tt2
    rgat_hop_kernel<false><<<hopGrid, blk, 0, stream>>>(
        ent, rel, Th1, Tt1, Tt2, RelC1, RelC2, rec, O, perm, out, SCP2, P2C, N);
    k_entity1<<<prepGrid, blk, 0, stream>>>((const float4*)out, (float4*)A, Tt2, ILAM2, N);

    // hop 2: overwrite d_out with sums2, then fuse residual in place
    rgat_hop_kernel<true><<<hopGrid, blk, 0, stream>>>(
        A, rel, Th1, Tt1, Tt2, RelC1, RelC2, rec, O, perm, out, SCP2, P2C, N);
    k_entity2<<<prepGrid, blk, 0, stream>>>((float4*)out, (const float4*)ent, (const float4*)A, N);
}

// Round 14
// 319.718 us; speedup vs baseline: 4.0950x; 1.1962x over previous
//
#include <hip/hip_runtime.h>
#include <cmath>

#define MIN_NORM 1e-15f
#define RCPF(x)  __builtin_amdgcn_rcpf(x)
#define SQRTF(x) __builtin_amdgcn_sqrtf(x)
#define RSQF(x)  __builtin_amdgcn_rsqf(x)

template<int CTRL>
__device__ __forceinline__ float dpp_add(float v) {
    return __int_as_float(__builtin_amdgcn_update_dpp(0, __float_as_int(v), CTRL, 0xF, 0xF, false));
}

__device__ __forceinline__ float rsum16(float v) {
    v += dpp_add<0x121>(v);
    v += dpp_add<0x122>(v);
    v += dpp_add<0x124>(v);
    v += dpp_add<0x128>(v);
    return v;
}

// butterfly sum across each adjacent-8-lane group
__device__ __forceinline__ float rsum8(float v) {
    v += dpp_add<0xB1>(v);   // quad_perm xor1
    v += dpp_add<0x4E>(v);   // quad_perm xor2
    v += dpp_add<0x141>(v);  // row_half_mirror
    return v;
}

__device__ __forceinline__ float tanh_fast(float x) {
    float ex = __expf(fminf(2.f * x, 30.f));
    return (ex - 1.f) * RCPF(ex + 1.f);
}

// ---------------- CSR build (count/scan/scatter) ----------------
__global__ __launch_bounds__(256) void k_count(const int* __restrict__ head,
                                               int* __restrict__ C, int E) {
    int i = blockIdx.x * 256 + (int)threadIdx.x;
    if (i < E) atomicAdd(&C[head[i]], 1);
}

__global__ __launch_bounds__(256) void k_scan1(const int* __restrict__ C,
                                               int* __restrict__ T,
                                               int* __restrict__ BS, int N) {
    __shared__ int lds[256];
    int i = blockIdx.x * 256 + (int)threadIdx.x;
    int v = (i < N) ? C[i] : 0;
    lds[threadIdx.x] = v;
    __syncthreads();
    for (int off = 1; off < 256; off <<= 1) {
        int add = (threadIdx.x >= (unsigned)off) ? lds[threadIdx.x - off] : 0;
        __syncthreads();
        lds[threadIdx.x] += add;
        __syncthreads();
    }
    if (i < N) T[i] = lds[threadIdx.x];
    if (threadIdx.x == 255) BS[blockIdx.x] = lds[255];
}

__global__ __launch_bounds__(1024) void k_scan2(int* __restrict__ BS, int nb) {
    __shared__ int lds[1024];
    int v = ((int)threadIdx.x < nb) ? BS[threadIdx.x] : 0;
    lds[threadIdx.x] = v;
    __syncthreads();
    for (int off = 1; off < 1024; off <<= 1) {
        int add = (threadIdx.x >= (unsigned)off) ? lds[threadIdx.x - off] : 0;
        __syncthreads();
        lds[threadIdx.x] += add;
        __syncthreads();
    }
    if ((int)threadIdx.x < nb) BS[threadIdx.x] = lds[threadIdx.x] - v;
}

// O = exclusive offsets (+O[N]=E), P = cursor copy, + degree histogram (descending buckets)
__global__ __launch_bounds__(256) void k_scan3(const int* __restrict__ C,
                                               const int* __restrict__ T,
                                               const int* __restrict__ BS,
                                               int* __restrict__ O,
                                               int* __restrict__ P,
                                               int* __restrict__ DH, int N, int E) {
    __shared__ int lh[64];
    if (threadIdx.x < 64) lh[threadIdx.x] = 0;
    __syncthreads();
    int i = blockIdx.x * 256 + (int)threadIdx.x;
    if (i < N) {
        int c = C[i];
        int o = T[i] - c + BS[blockIdx.x];
        O[i] = o;
        P[i] = o;
        int bd = 63 - min(c, 63);          // descending degree buckets
        atomicAdd(&lh[bd], 1);
    }
    if (i == 0) O[N] = E;
    __syncthreads();
    if (threadIdx.x < 64 && lh[threadIdx.x] > 0)
        atomicAdd(&DH[threadIdx.x], lh[threadIdx.x]);
}

// rec packs tail | rtype<<20 (tail < 2^20, rtype < 32)
__global__ __launch_bounds__(256) void k_scatter(const int* __restrict__ head,
                                                 const int* __restrict__ tail,
                                                 const int* __restrict__ etype,
                                                 int* __restrict__ P,
                                                 int* __restrict__ rec, int E) {
    int i = blockIdx.x * 256 + (int)threadIdx.x;
    if (i < E) {
        int pos = atomicAdd(&P[head[i]], 1);
        rec[pos] = tail[i] | ((etype[i] - 1) << 20);
    }
}

// exclusive scan of DH[64] -> DB (cursors)
__global__ __launch_bounds__(64) void k_dscan(const int* __restrict__ DH,
                                              int* __restrict__ DB) {
    __shared__ int lds[64];
    int t = (int)threadIdx.x;
    int v = DH[t];
    lds[t] = v;
    __syncthreads();
    for (int off = 1; off < 64; off <<= 1) {
        int add = (t >= off) ? lds[t - off] : 0;
        __syncthreads();
        lds[t] += add;
        __syncthreads();
    }
    DB[t] = lds[t] - v;   // exclusive
}

__global__ __launch_bounds__(256) void k_dscatter(const int* __restrict__ C,
                                                  int* __restrict__ DB,
                                                  int* __restrict__ perm, int N) {
    __shared__ int lh[64];
    __shared__ int lbase[64];
    if (threadIdx.x < 64) lh[threadIdx.x] = 0;
    __syncthreads();
    int i = blockIdx.x * 256 + (int)threadIdx.x;
    int bd = -1, lr = 0;
    if (i < N) {
        bd = 63 - min(C[i], 63);
        lr = atomicAdd(&lh[bd], 1);
    }
    __syncthreads();
    if (threadIdx.x < 64 && lh[threadIdx.x] > 0)
        lbase[threadIdx.x] = atomicAdd(&DB[threadIdx.x], lh[threadIdx.x]);
    __syncthreads();
    if (bd >= 0) perm[lbase[bd] + lr] = i;
}

// ---------------- tables ----------------
__global__ __launch_bounds__(256) void k_prep(const float4* __restrict__ src,
                                              float2* __restrict__ Th1,
                                              float2* __restrict__ Tt1, int N) {
    int gid = (blockIdx.x * 256 + (int)threadIdx.x) >> 4;
    int g   = (int)threadIdx.x & 15;
    if (gid >= N) return;
    float4 v = src[(size_t)gid * 16 + g];
    float n2 = rsum16(v.x * v.x + v.y * v.y + v.z * v.z + v.w * v.w);
    if (g == 0) {
        float nh     = fmaxf(SQRTF(fmaxf(n2, 0.f)), MIN_NORM);
        float inv_nh = RCPF(nh);
        float th     = tanh_fast(nh);
        Th1[gid] = make_float2(th * inv_nh, th * th);
        Tt1[gid] = make_float2(nh, inv_nh);
    }
}

__global__ __launch_bounds__(256) void k_prep_rel(const float4* __restrict__ rel,
                                                  float2* __restrict__ RelC1,
                                                  float2* __restrict__ RelC2,
                                                  float ILAM2, int NR) {
    int gid = (blockIdx.x * 256 + (int)threadIdx.x) >> 4;
    int g   = (int)threadIdx.x & 15;
    if (gid >= NR) return;
    float4 v = rel[(size_t)gid * 16 + g];
    float n2 = rsum16(v.x * v.x + v.y * v.y + v.z * v.z + v.w * v.w);
    if (g == 0) {
        float nr = fmaxf(SQRTF(n2), MIN_NORM);
        float inv_nr = RCPF(nr);
        RelC1[gid] = make_float2(nr, inv_nr);
        float thr2 = tanh_fast(ILAM2 * nr);
        RelC2[gid] = make_float2(thr2 * inv_nr, thr2 * thr2);
    }
}

// ---- hop kernel: one 8-lane group per head; serial CSR run; fused epilogue ----
// lane = q*8 + l: q = head slot (0..7), l owns dims {l + 8k}, k=0..7
// HOP1: writes A = normalize(acc) and Tt2 table.
// HOP2: writes out = 0.25*ent + 0.5*hv(=A[h]) + normalize(acc).
template<bool HOP2>
__global__ __launch_bounds__(256) void rgat_hop_kernel(
    const float*  __restrict__ e,
    const float*  __restrict__ rel,
    const float2* __restrict__ Th1,
    const float2* __restrict__ Tt1,
    const float2* __restrict__ Tt2,
    const float2* __restrict__ RelC1,
    const float2* __restrict__ RelC2,
    const int*    __restrict__ rec,    // tail | rtype<<20, head-sorted
    const int*    __restrict__ O,      // [N+1]
    const int*    __restrict__ perm,   // [N] degree-desc head ids
    const float*  __restrict__ ent,    // hop2 only
    float*        __restrict__ dst0,   // hop1: A; hop2: out
    float2*       __restrict__ Tt2w,   // hop1 only
    float SCP2, float P2C, float ILAM2, int N)
{
    int tid  = blockIdx.x * 256 + (int)threadIdx.x;
    int slot = tid >> 3;               // global head slot
    int l    = (int)threadIdx.x & 7;
    bool act = slot < N;
    int h    = perm[act ? slot : 0];

    int beg = act ? O[h] : 0;
    int end = act ? O[h + 1] : 0;

    // head row + head-side scalars (once per head)
    const float* hrow = e + (size_t)h * 64 + l;
    float hv[8];
#pragma unroll
    for (int k = 0; k < 8; ++k) hv[k] = hrow[8 * k];

    float scp, p2;
    if constexpr (HOP2) {
        scp = SCP2; p2 = P2C;
    } else {
        float2 th = Th1[h];
        scp = th.x; p2 = th.y;
    }
    float bet  = fmaxf(1.f - p2, MIN_NORM);
    float ilam = RCPF(bet);
    float bet2 = bet * bet;

    float acc[8];
#pragma unroll
    for (int k = 0; k < 8; ++k) acc[k] = 0.f;

    float tA[8], rA[8], tB[8], rB[8];
    float2 tvA, rvA, tvB, rvB;

    auto LD = [&](int i, float* T, float* R, float2& TV, float2& RV) {
        int rc = rec[i];
        int ti = rc & 0xFFFFF;
        int ri = rc >> 20;
        const float* tr = e   + (size_t)ti * 64 + l;
        const float* rr = rel + (size_t)ri * 64 + l;
#pragma unroll
        for (int k = 0; k < 8; ++k) { T[k] = tr[8 * k]; R[k] = rr[8 * k]; }
        if constexpr (HOP2) { TV = Tt2[ti]; RV = RelC2[ri]; }
        else               { TV = Tt1[ti]; RV = RelC1[ri]; }
    };

    auto COMPUTE = [&](const float* t, const float* r, float2 tv, float2 rv) {
        float pht = 0.f, phr = 0.f, ptr_ = 0.f;
#pragma unroll
        for (int k = 0; k < 8; ++k) {
            pht  += hv[k] * t[k];
            phr  += hv[k] * r[k];
            ptr_ += t[k] * r[k];
        }
        float ht  = rsum8(pht);
        float hr  = rsum8(phr);
        float ttr = rsum8(ptr_);

        float sct, y2t, scr, y2r;
        if constexpr (HOP2) {
            sct = tv.x; y2t = tv.y;
            scr = rv.x; y2r = rv.y;
        } else {
            float tht = tanh_fast(ilam * tv.x);
            sct = tht * tv.y;  y2t = tht * tht;
            float thr_ = tanh_fast(ilam * rv.x);
            scr = thr_ * rv.y; y2r = thr_ * thr_;
        }

        float xyt = scp * sct * ht;
        float xyr = scp * scr * hr;

        float alt  = fmaf(2.f, xyt, 1.f + y2t);
        float dent = fmaxf(fmaf(p2, y2t, fmaf(2.f, xyt, 1.f)), MIN_NORM);
        float alr  = fmaf(2.f, xyr, 1.f + y2r);
        float denr = fmaxf(fmaf(p2, y2r, fmaf(2.f, xyr, 1.f)), MIN_NORM);
        float iS   = RCPF(dent * denr);
        float idt  = iS * denr;
        float idr  = iS * dent;

        float a2 = (alt * alt * p2 + 2.f * alt * bet * xyt + bet * bet * y2t) * idt * idt;
        float pa = fmaf(bet, xyt, alt * p2) * idt;
        float b2 = (alr * alr * p2 + 2.f * alr * bet * xyr + bet * bet * y2r) * idr * idr;
        float pb = fmaf(bet, xyr, alr * p2) * idr;

        float ytyr = sct * scr * ttr;
        float ab = (alt * alr * p2 + alt * bet * xyr + bet * alr * xyt + bet * bet * ytyr) * idt * idr;

        float am   = fmaf(2.f, ab, 1.f + b2);
        float bm   = 1.f - a2;
        float denm = fmaxf(fmaf(a2, b2, fmaf(2.f, ab, 1.f)), MIN_NORM);
        float idm  = RCPF(denm);
        float m2  = (am * am * a2 + 2.f * am * bm * ab + bm * bm * b2) * idm * idm;
        float pmv = fmaf(am, pa, bm * pb) * idm;

        const float maxn  = 1.f - 4e-3f;
        const float maxn2 = maxn * maxn;
        float irm = RSQF(fmaxf(m2, 1e-30f));
        float sc  = (m2 > maxn2) ? (maxn * irm) : 1.f;
        m2  *= sc * sc;
        pmv *= sc;

        float cs   = fmaf(-2.f, pmv, 1.f + m2);
        float dens = fmaxf(fmaf(p2, m2, fmaf(-2.f, pmv, 1.f)), MIN_NORM);
        float ids  = RCPF(dens);
        float s2  = fmaxf((cs * cs * p2 - 2.f * cs * bet * pmv + bet * bet * m2) * ids * ids, 1e-30f);
        float irs = RSQF(s2);
        float ns  = s2 * irs;
        float xa  = fminf(ns, 1.f - 1e-7f);
        float ath = 0.5f * __logf((1.f + xa) * RCPF(1.f - xa));
        float lgs = bet * ath * irs;

        float X  = am * idt;
        float Y  = bm * idr;
        float G  = idm * sc;
        float W  = lgs * ids;
        float WG = W * G;
        float Kt = WG * X * bet2 * sct;
        float Kr = WG * Y * bet2 * scr;
        float Z  = WG * bet * fmaf(X, alt, Y * alr);
        float Kh = scp * (Z - W * cs);

#pragma unroll
        for (int k = 0; k < 8; ++k)
            acc[k] += fmaxf(fmaf(Kh, hv[k], fmaf(Kt, t[k], Kr * r[k])), 0.f);
    };

    // 2-stage pipelined run over this head's edges
    int i = beg;
    if (i < end) {
        LD(i, tA, rA, tvA, rvA);
        while (true) {
            if (i + 1 < end) LD(i + 1, tB, rB, tvB, rvB);
            COMPUTE(tA, rA, tvA, rvA);
            ++i;
            if (i >= end) break;
            if (i + 1 < end) LD(i + 1, tA, rA, tvA, rvA);
            COMPUTE(tB, rB, tvB, rvB);
            ++i;
            if (i >= end) break;
        }
    }

    if (!act) return;

    // ---- fused normalize epilogue ----
    float pn = 0.f;
#pragma unroll
    for (int k = 0; k < 8; ++k) pn += acc[k] * acc[k];
    float n2 = rsum8(pn);
    float sn = SQRTF(n2);
    float inv = RCPF(fmaxf(sn, 1e-12f));

    float* dst = dst0 + (size_t)h * 64 + l;
    if constexpr (HOP2) {
        const float* en = ent + (size_t)h * 64 + l;
#pragma unroll
        for (int k = 0; k < 8; ++k)
            dst[8 * k] = fmaf(0.25f, en[8 * k], fmaf(0.5f, hv[k], acc[k] * inv));
    } else {
#pragma unroll
        for (int k = 0; k < 8; ++k) dst[8 * k] = acc[k] * inv;
        if (l == 0) {
            float nv = sn * inv;               // 1 for nonzero rows, 0 for zero rows
            float nt = fmaxf(nv, MIN_NORM);
            float tht2 = tanh_fast(ILAM2 * nt);
            Tt2w[h] = make_float2(tht2 * RCPF(nt), tht2 * tht2);
        }
    }
}

extern "C" void kernel_launch(void* const* d_in, const int* in_sizes, int n_in,
                              void* d_out, int out_size, void* d_ws, size_t ws_size,
                              hipStream_t stream)
{
    const float* ent   = (const float*)d_in[0];
    const float* rel   = (const float*)d_in[1];
    const int*   eidx  = (const int*)d_in[2];
    const int*   etype = (const int*)d_in[3];

    int E = in_sizes[3];
    int N = in_sizes[0] / 64;
    int NR = in_sizes[1] / 64;
    const int* head = eidx;
    const int* tail = eidx + E;

    double th1d = tanh(1.0);
    float SCP2  = (float)th1d;
    float P2C   = (float)(th1d * th1d);
    float ILAM2 = (float)(1.0 / (1.0 - th1d * th1d));

    // ws: A[N*64] | rec[E] | O[N+1] | P,C,Tsc,perm[N] | Th1,Tt1,Tt2[N f2] | RelC | DH,DB | BS
    float*  A     = (float*)d_ws;                      // 51.2 MB
    int*    rec   = (int*)(A + (size_t)N * 64);        // 4 MB
    int*    O     = rec + E;
    int*    P     = O + (N + 1);
    int*    C     = P + N;
    int*    Tsc   = C + N;
    int*    perm  = Tsc + N;
    float2* Th1   = (float2*)(perm + N);
    float2* Tt1   = Th1 + N;
    float2* Tt2   = Tt1 + N;
    float2* RelC1 = Tt2 + N;
    float2* RelC2 = RelC1 + NR;
    int*    DH    = (int*)(RelC2 + NR);                // 64
    int*    DB    = DH + 64;                           // 64
    int*    BS    = DB + 64;                           // <=1024

    int NB = (N + 255) / 256;
    int EB = (E + 255) / 256;

    float* out = (float*)d_out;

    dim3 blk(256);
    int prepGrid = (N * 16 + 255) / 256;
    int relGrid  = (NR * 16 + 255) / 256;
    int hopGrid  = (N * 8 + 255) / 256;    // 8 lanes per head

    // CSR build + degree histogram
    (void)hipMemsetAsync(C, 0, (size_t)N * sizeof(int), stream);
    (void)hipMemsetAsync(DH, 0, 128 * sizeof(int), stream);
    k_count  <<<EB, blk, 0, stream>>>(head, C, E);
    k_scan1  <<<NB, blk, 0, stream>>>(C, Tsc, BS, N);
    k_scan2  <<<1, 1024, 0, stream>>>(BS, NB);
    k_scan3  <<<NB, blk, 0, stream>>>(C, Tsc, BS, O, P, DH, N, E);
    k_scatter<<<EB, blk, 0, stream>>>(head, tail, etype, P, rec, E);

    // degree-descending head permutation
    k_dscan   <<<1, 64, 0, stream>>>(DH, DB);
    k_dscatter<<<NB, blk, 0, stream>>>(C, DB, perm, N);

    // tables
    k_prep    <<<prepGrid, blk, 0, stream>>>((const float4*)ent, Th1, Tt1, N);
    k_prep_rel<<<relGrid,  blk, 0, stream>>>((const float4*)rel, RelC1, RelC2, ILAM2, NR);

    // hop 1: fused normalize -> A + Tt2
    rgat_hop_kernel<false><<<hopGrid, blk, 0, stream>>>(
        ent, rel, Th1, Tt1, Tt2, RelC1, RelC2, rec, O, perm,
        nullptr, A, Tt2, SCP2, P2C, ILAM2, N);

    // hop 2: fused residual -> out
    rgat_hop_kernel<true><<<hopGrid, blk, 0, stream>>>(
        A, rel, Th1, Tt1, Tt2, RelC1, RelC2, rec, O, perm,
        ent, out, nullptr, SCP2, P2C, ILAM2, N);
}

// Round 15
// 294.066 us; speedup vs baseline: 4.4522x; 1.0872x over previous
//
#include <hip/hip_runtime.h>
#include <cmath>

#define MIN_NORM 1e-15f
#define RCPF(x)  __builtin_amdgcn_rcpf(x)
#define SQRTF(x) __builtin_amdgcn_sqrtf(x)
#define RSQF(x)  __builtin_amdgcn_rsqf(x)

template<int CTRL>
__device__ __forceinline__ float dpp_add(float v) {
    return __int_as_float(__builtin_amdgcn_update_dpp(0, __float_as_int(v), CTRL, 0xF, 0xF, false));
}

__device__ __forceinline__ float rsum16(float v) {
    v += dpp_add<0x121>(v);
    v += dpp_add<0x122>(v);
    v += dpp_add<0x124>(v);
    v += dpp_add<0x128>(v);
    return v;
}

__device__ __forceinline__ float rsum8(float v) {
    v += dpp_add<0xB1>(v);   // quad_perm xor1
    v += dpp_add<0x4E>(v);   // quad_perm xor2
    v += dpp_add<0x141>(v);  // row_half_mirror
    return v;
}

__device__ __forceinline__ float tanh_fast(float x) {
    float ex = __expf(fminf(2.f * x, 30.f));
    return (ex - 1.f) * RCPF(ex + 1.f);
}

// ---- fused pass 1: [0,EB) count | [EB,EB+PG) entity tables | [EB+PG,..) rel tables ----
__global__ __launch_bounds__(256) void k_pass1(
    const int*    __restrict__ head,
    const float4* __restrict__ ent,
    const float4* __restrict__ rel,
    int*    __restrict__ C,
    float2* __restrict__ Th1,
    float2* __restrict__ Tt1,
    float2* __restrict__ RelC1,
    float2* __restrict__ RelC2,
    float ILAM2, int E, int N, int NR, int EB, int PG)
{
    int b = (int)blockIdx.x;
    if (b < EB) {
        int i = b * 256 + (int)threadIdx.x;
        if (i < E) atomicAdd(&C[head[i]], 1);
    } else if (b < EB + PG) {
        int gid = ((b - EB) * 256 + (int)threadIdx.x) >> 4;
        int g   = (int)threadIdx.x & 15;
        if (gid >= N) return;
        float4 v = ent[(size_t)gid * 16 + g];
        float n2 = rsum16(v.x * v.x + v.y * v.y + v.z * v.z + v.w * v.w);
        if (g == 0) {
            float nh     = fmaxf(SQRTF(fmaxf(n2, 0.f)), MIN_NORM);
            float inv_nh = RCPF(nh);
            float th     = tanh_fast(nh);
            Th1[gid] = make_float2(th * inv_nh, th * th);
            Tt1[gid] = make_float2(nh, inv_nh);
        }
    } else {
        int gid = ((b - EB - PG) * 256 + (int)threadIdx.x) >> 4;
        int g   = (int)threadIdx.x & 15;
        if (gid >= NR) return;
        float4 v = rel[(size_t)gid * 16 + g];
        float n2 = rsum16(v.x * v.x + v.y * v.y + v.z * v.z + v.w * v.w);
        if (g == 0) {
            float nr = fmaxf(SQRTF(n2), MIN_NORM);
            float inv_nr = RCPF(nr);
            RelC1[gid] = make_float2(nr, inv_nr);
            float thr2 = tanh_fast(ILAM2 * nr);
            RelC2[gid] = make_float2(thr2 * inv_nr, thr2 * thr2);
        }
    }
}

// ---- offsets: block scan of C + atomic global cursor (unordered CSR base),
//      writes OC={beg,cnt}, P=beg, degree histogram DH ----
__global__ __launch_bounds__(256) void k_offsets(
    const int* __restrict__ C,
    int*  __restrict__ CUR,
    int2* __restrict__ OC,
    int*  __restrict__ P,
    int*  __restrict__ DH, int N)
{
    __shared__ int lds[256];
    __shared__ int lh[64];
    __shared__ int base;
    if (threadIdx.x < 64) lh[threadIdx.x] = 0;
    int i = blockIdx.x * 256 + (int)threadIdx.x;
    int v = (i < N) ? C[i] : 0;
    lds[threadIdx.x] = v;
    __syncthreads();
    for (int off = 1; off < 256; off <<= 1) {
        int add = (threadIdx.x >= (unsigned)off) ? lds[threadIdx.x - off] : 0;
        __syncthreads();
        lds[threadIdx.x] += add;
        __syncthreads();
    }
    if (threadIdx.x == 255) base = atomicAdd(CUR, lds[255]);
    __syncthreads();
    if (i < N) {
        int beg = base + lds[threadIdx.x] - v;
        OC[i] = make_int2(beg, v);
        P[i] = beg;
        int bd = 63 - min(v, 63);     // descending-degree bucket
        atomicAdd(&lh[bd], 1);
    }
    __syncthreads();
    if (threadIdx.x < 64 && lh[threadIdx.x] > 0)
        atomicAdd(&DH[threadIdx.x], lh[threadIdx.x]);
}

// exclusive scan of DH[64] -> DB
__global__ __launch_bounds__(64) void k_dscan(const int* __restrict__ DH,
                                              int* __restrict__ DB) {
    __shared__ int lds[64];
    int t = (int)threadIdx.x;
    int v = DH[t];
    lds[t] = v;
    __syncthreads();
    for (int off = 1; off < 64; off <<= 1) {
        int add = (t >= off) ? lds[t - off] : 0;
        __syncthreads();
        lds[t] += add;
        __syncthreads();
    }
    DB[t] = lds[t] - v;
}

// ---- fused pass 2: [0,NB) degree-bucket scatter of perm | [NB,..) edge scatter ----
__global__ __launch_bounds__(256) void k_pass2(
    const int* __restrict__ C,
    int*       __restrict__ DB,
    int*       __restrict__ perm,
    const int* __restrict__ head,
    const int* __restrict__ tail,
    const int* __restrict__ etype,
    int*       __restrict__ P,
    int*       __restrict__ rec,
    int N, int E, int NB)
{
    int b = (int)blockIdx.x;
    if (b < NB) {
        __shared__ int lh[64];
        __shared__ int lbase[64];
        if (threadIdx.x < 64) lh[threadIdx.x] = 0;
        __syncthreads();
        int i = b * 256 + (int)threadIdx.x;
        int bd = -1, lr = 0;
        if (i < N) {
            bd = 63 - min(C[i], 63);
            lr = atomicAdd(&lh[bd], 1);
        }
        __syncthreads();
        if (threadIdx.x < 64 && lh[threadIdx.x] > 0)
            lbase[threadIdx.x] = atomicAdd(&DB[threadIdx.x], lh[threadIdx.x]);
        __syncthreads();
        if (bd >= 0) perm[lbase[bd] + lr] = i;
    } else {
        int i = (b - NB) * 256 + (int)threadIdx.x;
        if (i < E) {
            int pos = atomicAdd(&P[head[i]], 1);
            rec[pos] = tail[i] | ((etype[i] - 1) << 20);
        }
    }
}

// ---- hop kernel: one 8-lane group per head; serial CSR run; fused epilogue ----
template<bool HOP2>
__global__ __launch_bounds__(256) void rgat_hop_kernel(
    const float*  __restrict__ e,
    const float*  __restrict__ rel,
    const float2* __restrict__ Th1,
    const float2* __restrict__ Tt1,
    const float2* __restrict__ Tt2,
    const float2* __restrict__ RelC1,
    const float2* __restrict__ RelC2,
    const int*    __restrict__ rec,    // tail | rtype<<20, head-grouped
    const int2*   __restrict__ OC,     // [N] {beg, cnt}
    const int*    __restrict__ perm,   // [N] degree-desc head ids
    const float*  __restrict__ ent,    // hop2 only
    float*        __restrict__ dst0,   // hop1: A; hop2: out
    float2*       __restrict__ Tt2w,   // hop1 only
    float SCP2, float P2C, float ILAM2, int N)
{
    int tid  = blockIdx.x * 256 + (int)threadIdx.x;
    int slot = tid >> 3;
    int l    = (int)threadIdx.x & 7;
    bool act = slot < N;
    int h    = perm[act ? slot : 0];

    int2 oc = OC[h];
    int beg = act ? oc.x : 0;
    int end = act ? (oc.x + oc.y) : 0;

    const float* hrow = e + (size_t)h * 64 + l;
    float hv[8];
#pragma unroll
    for (int k = 0; k < 8; ++k) hv[k] = hrow[8 * k];

    float scp, p2;
    if constexpr (HOP2) {
        scp = SCP2; p2 = P2C;
    } else {
        float2 th = Th1[h];
        scp = th.x; p2 = th.y;
    }
    float bet  = fmaxf(1.f - p2, MIN_NORM);
    float ilam = RCPF(bet);
    float bet2 = bet * bet;

    float acc[8];
#pragma unroll
    for (int k = 0; k < 8; ++k) acc[k] = 0.f;

    float tA[8], rA[8], tB[8], rB[8];
    float2 tvA, rvA, tvB, rvB;

    auto LD = [&](int i, float* T, float* R, float2& TV, float2& RV) {
        int rc = rec[i];
        int ti = rc & 0xFFFFF;
        int ri = rc >> 20;
        const float* tr = e   + (size_t)ti * 64 + l;
        const float* rr = rel + (size_t)ri * 64 + l;
#pragma unroll
        for (int k = 0; k < 8; ++k) { T[k] = tr[8 * k]; R[k] = rr[8 * k]; }
        if constexpr (HOP2) { TV = Tt2[ti]; RV = RelC2[ri]; }
        else               { TV = Tt1[ti]; RV = RelC1[ri]; }
    };

    auto COMPUTE = [&](const float* t, const float* r, float2 tv, float2 rv) {
        float pht = 0.f, phr = 0.f, ptr_ = 0.f;
#pragma unroll
        for (int k = 0; k < 8; ++k) {
            pht  += hv[k] * t[k];
            phr  += hv[k] * r[k];
            ptr_ += t[k] * r[k];
        }
        float ht  = rsum8(pht);
        float hr  = rsum8(phr);
        float ttr = rsum8(ptr_);

        float sct, y2t, scr, y2r;
        if constexpr (HOP2) {
            sct = tv.x; y2t = tv.y;
            scr = rv.x; y2r = rv.y;
        } else {
            float tht = tanh_fast(ilam * tv.x);
            sct = tht * tv.y;  y2t = tht * tht;
            float thr_ = tanh_fast(ilam * rv.x);
            scr = thr_ * rv.y; y2r = thr_ * thr_;
        }

        float xyt = scp * sct * ht;
        float xyr = scp * scr * hr;

        float alt  = fmaf(2.f, xyt, 1.f + y2t);
        float dent = fmaxf(fmaf(p2, y2t, fmaf(2.f, xyt, 1.f)), MIN_NORM);
        float alr  = fmaf(2.f, xyr, 1.f + y2r);
        float denr = fmaxf(fmaf(p2, y2r, fmaf(2.f, xyr, 1.f)), MIN_NORM);
        float iS   = RCPF(dent * denr);
        float idt  = iS * denr;
        float idr  = iS * dent;

        float a2 = (alt * alt * p2 + 2.f * alt * bet * xyt + bet * bet * y2t) * idt * idt;
        float pa = fmaf(bet, xyt, alt * p2) * idt;
        float b2 = (alr * alr * p2 + 2.f * alr * bet * xyr + bet * bet * y2r) * idr * idr;
        float pb = fmaf(bet, xyr, alr * p2) * idr;

        float ytyr = sct * scr * ttr;
        float ab = (alt * alr * p2 + alt * bet * xyr + bet * alr * xyt + bet * bet * ytyr) * idt * idr;

        float am   = fmaf(2.f, ab, 1.f + b2);
        float bm   = 1.f - a2;
        float denm = fmaxf(fmaf(a2, b2, fmaf(2.f, ab, 1.f)), MIN_NORM);
        float idm  = RCPF(denm);
        float m2  = (am * am * a2 + 2.f * am * bm * ab + bm * bm * b2) * idm * idm;
        float pmv = fmaf(am, pa, bm * pb) * idm;

        const float maxn  = 1.f - 4e-3f;
        const float maxn2 = maxn * maxn;
        float irm = RSQF(fmaxf(m2, 1e-30f));
        float sc  = (m2 > maxn2) ? (maxn * irm) : 1.f;
        m2  *= sc * sc;
        pmv *= sc;

        float cs   = fmaf(-2.f, pmv, 1.f + m2);
        float dens = fmaxf(fmaf(p2, m2, fmaf(-2.f, pmv, 1.f)), MIN_NORM);
        float ids  = RCPF(dens);
        float s2  = fmaxf((cs * cs * p2 - 2.f * cs * bet * pmv + bet * bet * m2) * ids * ids, 1e-30f);
        float irs = RSQF(s2);
        float ns  = s2 * irs;
        float xa  = fminf(ns, 1.f - 1e-7f);
        float ath = 0.5f * __logf((1.f + xa) * RCPF(1.f - xa));
        float lgs = bet * ath * irs;

        float X  = am * idt;
        float Y  = bm * idr;
        float G  = idm * sc;
        float W  = lgs * ids;
        float WG = W * G;
        float Kt = WG * X * bet2 * sct;
        float Kr = WG * Y * bet2 * scr;
        float Z  = WG * bet * fmaf(X, alt, Y * alr);
        float Kh = scp * (Z - W * cs);

#pragma unroll
        for (int k = 0; k < 8; ++k)
            acc[k] += fmaxf(fmaf(Kh, hv[k], fmaf(Kt, t[k], Kr * r[k])), 0.f);
    };

    int i = beg;
    if (i < end) {
        LD(i, tA, rA, tvA, rvA);
        while (true) {
            if (i + 1 < end) LD(i + 1, tB, rB, tvB, rvB);
            COMPUTE(tA, rA, tvA, rvA);
            ++i;
            if (i >= end) break;
            if (i + 1 < end) LD(i + 1, tA, rA, tvA, rvA);
            COMPUTE(tB, rB, tvB, rvB);
            ++i;
            if (i >= end) break;
        }
    }

    if (!act) return;

    float pn = 0.f;
#pragma unroll
    for (int k = 0; k < 8; ++k) pn += acc[k] * acc[k];
    float n2 = rsum8(pn);
    float sn = SQRTF(n2);
    float inv = RCPF(fmaxf(sn, 1e-12f));

    float* dst = dst0 + (size_t)h * 64 + l;
    if constexpr (HOP2) {
        const float* en = ent + (size_t)h * 64 + l;
#pragma unroll
        for (int k = 0; k < 8; ++k)
            dst[8 * k] = fmaf(0.25f, en[8 * k], fmaf(0.5f, hv[k], acc[k] * inv));
    } else {
#pragma unroll
        for (int k = 0; k < 8; ++k) dst[8 * k] = acc[k] * inv;
        if (l == 0) {
            float nv = sn * inv;
            float nt = fmaxf(nv, MIN_NORM);
            float tht2 = tanh_fast(ILAM2 * nt);
            Tt2w[h] = make_float2(tht2 * RCPF(nt), tht2 * tht2);
        }
    }
}

extern "C" void kernel_launch(void* const* d_in, const int* in_sizes, int n_in,
                              void* d_out, int out_size, void* d_ws, size_t ws_size,
                              hipStream_t stream)
{
    const float* ent   = (const float*)d_in[0];
    const float* rel   = (const float*)d_in[1];
    const int*   eidx  = (const int*)d_in[2];
    const int*   etype = (const int*)d_in[3];

    int E = in_sizes[3];
    int N = in_sizes[0] / 64;
    int NR = in_sizes[1] / 64;
    const int* head = eidx;
    const int* tail = eidx + E;

    double th1d = tanh(1.0);
    float SCP2  = (float)th1d;
    float P2C   = (float)(th1d * th1d);
    float ILAM2 = (float)(1.0 / (1.0 - th1d * th1d));

    // ws: A[N*64] | rec[E] | OC[int2 N] | P[N] | C[N] DH[64] CUR[1] (one memset)
    //   | DB[64] | perm[N] | Th1,Tt1,Tt2[N f2] | RelC1,RelC2[NR f2]
    float*  A     = (float*)d_ws;
    int*    rec   = (int*)(A + (size_t)N * 64);
    int2*   OC    = (int2*)(rec + E);
    int*    P     = (int*)(OC + N);
    int*    C     = P + N;
    int*    DH    = C + N;
    int*    CUR   = DH + 64;
    int*    DB    = CUR + 1;
    int*    perm  = DB + 64;
    float2* Th1   = (float2*)(perm + N);
    float2* Tt1   = Th1 + N;
    float2* Tt2   = Tt1 + N;
    float2* RelC1 = Tt2 + N;
    float2* RelC2 = RelC1 + NR;

    int NB = (N + 255) / 256;
    int EB = (E + 255) / 256;
    int PG = (N * 16 + 255) / 256;
    int RG = (NR * 16 + 255) / 256;

    float* out = (float*)d_out;
    dim3 blk(256);
    int hopGrid = (N * 8 + 255) / 256;

    // one memset covers C[N] + DH[64] + CUR[1]
    (void)hipMemsetAsync(C, 0, (size_t)(N + 65) * sizeof(int), stream);

    k_pass1<<<EB + PG + RG, blk, 0, stream>>>(
        head, (const float4*)ent, (const float4*)rel,
        C, Th1, Tt1, RelC1, RelC2, ILAM2, E, N, NR, EB, PG);

    k_offsets<<<NB, blk, 0, stream>>>(C, CUR, OC, P, DH, N);
    k_dscan  <<<1, 64, 0, stream>>>(DH, DB);

    k_pass2<<<NB + EB, blk, 0, stream>>>(
        C, DB, perm, head, tail, etype, P, rec, N, E, NB);

    rgat_hop_kernel<false><<<hopGrid, blk, 0, stream>>>(
        ent, rel, Th1, Tt1, Tt2, RelC1, RelC2, rec, OC, perm,
        nullptr, A, Tt2, SCP2, P2C, ILAM2, N);

    rgat_hop_kernel<true><<<hopGrid, blk, 0, stream>>>(
        A, rel, Th1, Tt1, Tt2, RelC1, RelC2, rec, OC, perm,
        ent, out, nullptr, SCP2, P2C, ILAM2, N);
}

// Round 16
// 272.435 us; speedup vs baseline: 4.8057x; 1.0794x over previous
//
#include <hip/hip_runtime.h>
#include <cmath>

#define MIN_NORM 1e-15f
#define RCPF(x)  __builtin_amdgcn_rcpf(x)
#define SQRTF(x) __builtin_amdgcn_sqrtf(x)
#define RSQF(x)  __builtin_amdgcn_rsqf(x)

template<int CTRL>
__device__ __forceinline__ float dpp_add(float v) {
    return __int_as_float(__builtin_amdgcn_update_dpp(0, __float_as_int(v), CTRL, 0xF, 0xF, false));
}

__device__ __forceinline__ float rsum16(float v) {
    v += dpp_add<0x121>(v);
    v += dpp_add<0x122>(v);
    v += dpp_add<0x124>(v);
    v += dpp_add<0x128>(v);
    return v;
}

__device__ __forceinline__ float rsum8(float v) {
    v += dpp_add<0xB1>(v);   // quad_perm xor1
    v += dpp_add<0x4E>(v);   // quad_perm xor2
    v += dpp_add<0x141>(v);  // row_half_mirror
    return v;
}

__device__ __forceinline__ float tanh_fast(float x) {
    float ex = __expf(fminf(2.f * x, 30.f));
    return (ex - 1.f) * RCPF(ex + 1.f);
}

// ---- fused pass 1: [0,EB) count | [EB,EB+PG) entity tables | rest rel tables ----
__global__ __launch_bounds__(256) void k_pass1(
    const int*    __restrict__ head,
    const float4* __restrict__ ent,
    const float4* __restrict__ rel,
    int*    __restrict__ C,
    float2* __restrict__ Th1,
    float2* __restrict__ Tt1,
    float2* __restrict__ RelC1,
    float2* __restrict__ RelC2,
    float ILAM2, int E, int N, int NR, int EB, int PG)
{
    int b = (int)blockIdx.x;
    if (b < EB) {
        int i = b * 256 + (int)threadIdx.x;
        if (i < E) atomicAdd(&C[head[i]], 1);
    } else if (b < EB + PG) {
        int gid = ((b - EB) * 256 + (int)threadIdx.x) >> 4;
        int g   = (int)threadIdx.x & 15;
        if (gid >= N) return;
        float4 v = ent[(size_t)gid * 16 + g];
        float n2 = rsum16(v.x * v.x + v.y * v.y + v.z * v.z + v.w * v.w);
        if (g == 0) {
            float nh     = fmaxf(SQRTF(fmaxf(n2, 0.f)), MIN_NORM);
            float inv_nh = RCPF(nh);
            float th     = tanh_fast(nh);
            Th1[gid] = make_float2(th * inv_nh, th * th);
            Tt1[gid] = make_float2(nh, inv_nh);
        }
    } else {
        int gid = ((b - EB - PG) * 256 + (int)threadIdx.x) >> 4;
        int g   = (int)threadIdx.x & 15;
        if (gid >= NR) return;
        float4 v = rel[(size_t)gid * 16 + g];
        float n2 = rsum16(v.x * v.x + v.y * v.y + v.z * v.z + v.w * v.w);
        if (g == 0) {
            float nr = fmaxf(SQRTF(n2), MIN_NORM);
            float inv_nr = RCPF(nr);
            RelC1[gid] = make_float2(nr, inv_nr);
            float thr2 = tanh_fast(ILAM2 * nr);
            RelC2[gid] = make_float2(thr2 * inv_nr, thr2 * thr2);
        }
    }
}

// ---- scan1: per-block inclusive scan C -> T, block sums -> BS, + degree hist ----
__global__ __launch_bounds__(256) void k_scan1(const int* __restrict__ C,
                                               int* __restrict__ T,
                                               int* __restrict__ BS,
                                               int* __restrict__ DH, int N) {
    __shared__ int lds[256];
    __shared__ int lh[64];
    if (threadIdx.x < 64) lh[threadIdx.x] = 0;
    int i = blockIdx.x * 256 + (int)threadIdx.x;
    int v = (i < N) ? C[i] : 0;
    lds[threadIdx.x] = v;
    __syncthreads();
    for (int off = 1; off < 256; off <<= 1) {
        int add = (threadIdx.x >= (unsigned)off) ? lds[threadIdx.x - off] : 0;
        __syncthreads();
        lds[threadIdx.x] += add;
        __syncthreads();
    }
    if (i < N) {
        T[i] = lds[threadIdx.x];
        int bd = 63 - min(v, 63);          // descending-degree bucket
        atomicAdd(&lh[bd], 1);
    }
    if (threadIdx.x == 255) BS[blockIdx.x] = lds[255];
    __syncthreads();
    if (threadIdx.x < 64 && lh[threadIdx.x] > 0)
        atomicAdd(&DH[threadIdx.x], lh[threadIdx.x]);
}

// ---- scan2: block 0 scans BS[nb] (exclusive, 1024-wide); block 1 scans DH->DB ----
__global__ __launch_bounds__(1024) void k_scan2(int* __restrict__ BS,
                                                const int* __restrict__ DH,
                                                int* __restrict__ DB, int nb) {
    if (blockIdx.x == 0) {
        __shared__ int lds[1024];
        int v = ((int)threadIdx.x < nb) ? BS[threadIdx.x] : 0;
        lds[threadIdx.x] = v;
        __syncthreads();
        for (int off = 1; off < 1024; off <<= 1) {
            int add = (threadIdx.x >= (unsigned)off) ? lds[threadIdx.x - off] : 0;
            __syncthreads();
            lds[threadIdx.x] += add;
            __syncthreads();
        }
        if ((int)threadIdx.x < nb) BS[threadIdx.x] = lds[threadIdx.x] - v;
    } else {
        __shared__ int lds[64];
        if (threadIdx.x >= 64) return;
        int t = (int)threadIdx.x;
        int v = DH[t];
        lds[t] = v;
        __syncthreads();
        for (int off = 1; off < 64; off <<= 1) {
            int add = (t >= off) ? lds[t - off] : 0;
            __syncthreads();
            lds[t] += add;
            __syncthreads();
        }
        DB[t] = lds[t] - v;
    }
}

// ---- scan3: ordered offsets OC={beg,cnt}, P=beg ----
__global__ __launch_bounds__(256) void k_scan3(const int* __restrict__ C,
                                               const int* __restrict__ T,
                                               const int* __restrict__ BS,
                                               int2* __restrict__ OC,
                                               int* __restrict__ P, int N) {
    int i = blockIdx.x * 256 + (int)threadIdx.x;
    if (i < N) {
        int c = C[i];
        int beg = T[i] - c + BS[blockIdx.x];
        OC[i] = make_int2(beg, c);
        P[i] = beg;
    }
}

// ---- fused pass 2: [0,NB) perm dscatter | [NB,..) region-routed edge scatter ----
// Scatter blocks: region = blockIdx%8 (XCD-aligned heuristic), stripe = (b-NB)>>3.
// Region r owns heads [r*N/8,(r+1)*N/8) whose rec positions are CONTIGUOUS
// (ordered CSR) -> each region's writes stay in a ~E/8*4B window, lines fill
// completely before eviction -> full-line writebacks instead of 16x amplification.
__global__ __launch_bounds__(256) void k_pass2(
    const int* __restrict__ C,
    int*       __restrict__ DB,
    int*       __restrict__ perm,
    const int* __restrict__ head,
    const int* __restrict__ tail,
    const int* __restrict__ etype,
    int*       __restrict__ P,
    int*       __restrict__ rec,
    int N, int E, int NB, int SLICES)
{
    int b = (int)blockIdx.x;
    if (b < NB) {
        __shared__ int lh[64];
        __shared__ int lbase[64];
        if (threadIdx.x < 64) lh[threadIdx.x] = 0;
        __syncthreads();
        int i = b * 256 + (int)threadIdx.x;
        int bd = -1, lr = 0;
        if (i < N) {
            bd = 63 - min(C[i], 63);
            lr = atomicAdd(&lh[bd], 1);
        }
        __syncthreads();
        if (threadIdx.x < 64 && lh[threadIdx.x] > 0)
            lbase[threadIdx.x] = atomicAdd(&DB[threadIdx.x], lh[threadIdx.x]);
        __syncthreads();
        if (bd >= 0) perm[lbase[bd] + lr] = i;
    } else {
        int region = b & 7;
        int slice  = (b - NB) >> 3;
        int rlo = (int)(((long long)region * N) >> 3);
        int rhi = (int)(((long long)(region + 1) * N) >> 3);
        int step = 256 * SLICES;
        for (int i = slice * 256 + (int)threadIdx.x; i < E; i += step) {
            int h = head[i];
            int t = tail[i];
            int et = etype[i];
            if (h >= rlo && h < rhi) {
                int pos = atomicAdd(&P[h], 1);
                rec[pos] = t | ((et - 1) << 20);
            }
        }
    }
}

// ---- hop kernel: one 8-lane group per head; serial CSR run; fused epilogue ----
template<bool HOP2>
__global__ __launch_bounds__(256) void rgat_hop_kernel(
    const float*  __restrict__ e,
    const float*  __restrict__ rel,
    const float2* __restrict__ Th1,
    const float2* __restrict__ Tt1,
    const float2* __restrict__ Tt2,
    const float2* __restrict__ RelC1,
    const float2* __restrict__ RelC2,
    const int*    __restrict__ rec,    // tail | rtype<<20, head-grouped
    const int2*   __restrict__ OC,     // [N] {beg, cnt}
    const int*    __restrict__ perm,   // [N] degree-desc head ids
    const float*  __restrict__ ent,    // hop2 only
    float*        __restrict__ dst0,   // hop1: A; hop2: out
    float2*       __restrict__ Tt2w,   // hop1 only
    float SCP2, float P2C, float ILAM2, int N)
{
    int tid  = blockIdx.x * 256 + (int)threadIdx.x;
    int slot = tid >> 3;
    int l    = (int)threadIdx.x & 7;
    bool act = slot < N;
    int h    = perm[act ? slot : 0];

    int2 oc = OC[h];
    int beg = act ? oc.x : 0;
    int end = act ? (oc.x + oc.y) : 0;

    const float* hrow = e + (size_t)h * 64 + l;
    float hv[8];
#pragma unroll
    for (int k = 0; k < 8; ++k) hv[k] = hrow[8 * k];

    float scp, p2;
    if constexpr (HOP2) {
        scp = SCP2; p2 = P2C;
    } else {
        float2 th = Th1[h];
        scp = th.x; p2 = th.y;
    }
    float bet  = fmaxf(1.f - p2, MIN_NORM);
    float ilam = RCPF(bet);
    float bet2 = bet * bet;

    float acc[8];
#pragma unroll
    for (int k = 0; k < 8; ++k) acc[k] = 0.f;

    float tA[8], rA[8], tB[8], rB[8];
    float2 tvA, rvA, tvB, rvB;

    auto LD = [&](int i, float* T, float* R, float2& TV, float2& RV) {
        int rc = rec[i];
        int ti = rc & 0xFFFFF;
        int ri = rc >> 20;
        const float* tr = e   + (size_t)ti * 64 + l;
        const float* rr = rel + (size_t)ri * 64 + l;
#pragma unroll
        for (int k = 0; k < 8; ++k) { T[k] = tr[8 * k]; R[k] = rr[8 * k]; }
        if constexpr (HOP2) { TV = Tt2[ti]; RV = RelC2[ri]; }
        else               { TV = Tt1[ti]; RV = RelC1[ri]; }
    };

    auto COMPUTE = [&](const float* t, const float* r, float2 tv, float2 rv) {
        float pht = 0.f, phr = 0.f, ptr_ = 0.f;
#pragma unroll
        for (int k = 0; k < 8; ++k) {
            pht  += hv[k] * t[k];
            phr  += hv[k] * r[k];
            ptr_ += t[k] * r[k];
        }
        float ht  = rsum8(pht);
        float hr  = rsum8(phr);
        float ttr = rsum8(ptr_);

        float sct, y2t, scr, y2r;
        if constexpr (HOP2) {
            sct = tv.x; y2t = tv.y;
            scr = rv.x; y2r = rv.y;
        } else {
            float tht = tanh_fast(ilam * tv.x);
            sct = tht * tv.y;  y2t = tht * tht;
            float thr_ = tanh_fast(ilam * rv.x);
            scr = thr_ * rv.y; y2r = thr_ * thr_;
        }

        float xyt = scp * sct * ht;
        float xyr = scp * scr * hr;

        float alt  = fmaf(2.f, xyt, 1.f + y2t);
        float dent = fmaxf(fmaf(p2, y2t, fmaf(2.f, xyt, 1.f)), MIN_NORM);
        float alr  = fmaf(2.f, xyr, 1.f + y2r);
        float denr = fmaxf(fmaf(p2, y2r, fmaf(2.f, xyr, 1.f)), MIN_NORM);
        float iS   = RCPF(dent * denr);
        float idt  = iS * denr;
        float idr  = iS * dent;

        float a2 = (alt * alt * p2 + 2.f * alt * bet * xyt + bet * bet * y2t) * idt * idt;
        float pa = fmaf(bet, xyt, alt * p2) * idt;
        float b2 = (alr * alr * p2 + 2.f * alr * bet * xyr + bet * bet * y2r) * idr * idr;
        float pb = fmaf(bet, xyr, alr * p2) * idr;

        float ytyr = sct * scr * ttr;
        float ab = (alt * alr * p2 + alt * bet * xyr + bet * alr * xyt + bet * bet * ytyr) * idt * idr;

        float am   = fmaf(2.f, ab, 1.f + b2);
        float bm   = 1.f - a2;
        float denm = fmaxf(fmaf(a2, b2, fmaf(2.f, ab, 1.f)), MIN_NORM);
        float idm  = RCPF(denm);
        float m2  = (am * am * a2 + 2.f * am * bm * ab + bm * bm * b2) * idm * idm;
        float pmv = fmaf(am, pa, bm * pb) * idm;

        const float maxn  = 1.f - 4e-3f;
        const float maxn2 = maxn * maxn;
        float irm = RSQF(fmaxf(m2, 1e-30f));
        float sc  = (m2 > maxn2) ? (maxn * irm) : 1.f;
        m2  *= sc * sc;
        pmv *= sc;

        float cs   = fmaf(-2.f, pmv, 1.f + m2);
        float dens = fmaxf(fmaf(p2, m2, fmaf(-2.f, pmv, 1.f)), MIN_NORM);
        float ids  = RCPF(dens);
        float s2  = fmaxf((cs * cs * p2 - 2.f * cs * bet * pmv + bet * bet * m2) * ids * ids, 1e-30f);
        float irs = RSQF(s2);
        float ns  = s2 * irs;
        float xa  = fminf(ns, 1.f - 1e-7f);
        float ath = 0.5f * __logf((1.f + xa) * RCPF(1.f - xa));
        float lgs = bet * ath * irs;

        float X  = am * idt;
        float Y  = bm * idr;
        float G  = idm * sc;
        float W  = lgs * ids;
        float WG = W * G;
        float Kt = WG * X * bet2 * sct;
        float Kr = WG * Y * bet2 * scr;
        float Z  = WG * bet * fmaf(X, alt, Y * alr);
        float Kh = scp * (Z - W * cs);

#pragma unroll
        for (int k = 0; k < 8; ++k)
            acc[k] += fmaxf(fmaf(Kh, hv[k], fmaf(Kt, t[k], Kr * r[k])), 0.f);
    };

    int i = beg;
    if (i < end) {
        LD(i, tA, rA, tvA, rvA);
        while (true) {
            if (i + 1 < end) LD(i + 1, tB, rB, tvB, rvB);
            COMPUTE(tA, rA, tvA, rvA);
            ++i;
            if (i >= end) break;
            if (i + 1 < end) LD(i + 1, tA, rA, tvA, rvA);
            COMPUTE(tB, rB, tvB, rvB);
            ++i;
            if (i >= end) break;
        }
    }

    if (!act) return;

    float pn = 0.f;
#pragma unroll
    for (int k = 0; k < 8; ++k) pn += acc[k] * acc[k];
    float n2 = rsum8(pn);
    float sn = SQRTF(n2);
    float inv = RCPF(fmaxf(sn, 1e-12f));

    float* dst = dst0 + (size_t)h * 64 + l;
    if constexpr (HOP2) {
        const float* en = ent + (size_t)h * 64 + l;
#pragma unroll
        for (int k = 0; k < 8; ++k)
            dst[8 * k] = fmaf(0.25f, en[8 * k], fmaf(0.5f, hv[k], acc[k] * inv));
    } else {
#pragma unroll
        for (int k = 0; k < 8; ++k) dst[8 * k] = acc[k] * inv;
        if (l == 0) {
            float nv = sn * inv;
            float nt = fmaxf(nv, MIN_NORM);
            float tht2 = tanh_fast(ILAM2 * nt);
            Tt2w[h] = make_float2(tht2 * RCPF(nt), tht2 * tht2);
        }
    }
}

extern "C" void kernel_launch(void* const* d_in, const int* in_sizes, int n_in,
                              void* d_out, int out_size, void* d_ws, size_t ws_size,
                              hipStream_t stream)
{
    const float* ent   = (const float*)d_in[0];
    const float* rel   = (const float*)d_in[1];
    const int*   eidx  = (const int*)d_in[2];
    const int*   etype = (const int*)d_in[3];

    int E = in_sizes[3];
    int N = in_sizes[0] / 64;
    int NR = in_sizes[1] / 64;
    const int* head = eidx;
    const int* tail = eidx + E;

    double th1d = tanh(1.0);
    float SCP2  = (float)th1d;
    float P2C   = (float)(th1d * th1d);
    float ILAM2 = (float)(1.0 / (1.0 - th1d * th1d));

    // ws: A[N*64] | rec[E] | OC[int2 N] | P[N] | C[N] DH[64] (one memset) | T[N]
    //   | BS[1024] | DB[64] | perm[N] | Th1,Tt1,Tt2[N f2] | RelC1,RelC2[NR f2]
    float*  A     = (float*)d_ws;
    int*    rec   = (int*)(A + (size_t)N * 64);
    int2*   OC    = (int2*)(rec + E);
    int*    P     = (int*)(OC + N);
    int*    C     = P + N;
    int*    DH    = C + N;
    int*    T     = DH + 64;
    int*    BS    = T + N;
    int*    DB    = BS + 1024;
    int*    perm  = DB + 64;
    float2* Th1   = (float2*)(perm + N);
    float2* Tt1   = Th1 + N;
    float2* Tt2   = Tt1 + N;
    float2* RelC1 = Tt2 + N;
    float2* RelC2 = RelC1 + NR;

    int NB = (N + 255) / 256;
    int EB = (E + 255) / 256;
    int PG = (N * 16 + 255) / 256;
    int RG = (NR * 16 + 255) / 256;
    const int SLICES = 104;              // 832 region-routed scatter blocks

    float* out = (float*)d_out;
    dim3 blk(256);
    int hopGrid = (N * 8 + 255) / 256;

    // one memset covers C[N] + DH[64]
    (void)hipMemsetAsync(C, 0, (size_t)(N + 64) * sizeof(int), stream);

    k_pass1<<<EB + PG + RG, blk, 0, stream>>>(
        head, (const float4*)ent, (const float4*)rel,
        C, Th1, Tt1, RelC1, RelC2, ILAM2, E, N, NR, EB, PG);

    k_scan1<<<NB, blk, 0, stream>>>(C, T, BS, DH, N);
    k_scan2<<<2, 1024, 0, stream>>>(BS, DH, DB, NB);
    k_scan3<<<NB, blk, 0, stream>>>(C, T, BS, OC, P, N);

    k_pass2<<<NB + 8 * SLICES, blk, 0, stream>>>(
        C, DB, perm, head, tail, etype, P, rec, N, E, NB, SLICES);

    rgat_hop_kernel<false><<<hopGrid, blk, 0, stream>>>(
        ent, rel, Th1, Tt1, Tt2, RelC1, RelC2, rec, OC, perm,
        nullptr, A, Tt2, SCP2, P2C, ILAM2, N);

    rgat_hop_kernel<true><<<hopGrid, blk, 0, stream>>>(
        A, rel, Th1, Tt1, Tt2, RelC1, RelC2, rec, OC, perm,
        ent, out, nullptr, SCP2, P2C, ILAM2, N);
}

// Round 17
// 258.368 us; speedup vs baseline: 5.0673x; 1.0544x over previous
//
#include <hip/hip_runtime.h>
#include <hip/hip_fp16.h>
#include <cmath>

#define MIN_NORM 1e-15f
#define RCPF(x)  __builtin_amdgcn_rcpf(x)
#define SQRTF(x) __builtin_amdgcn_sqrtf(x)
#define RSQF(x)  __builtin_amdgcn_rsqf(x)

template<int CTRL>
__device__ __forceinline__ float dpp_add(float v) {
    return __int_as_float(__builtin_amdgcn_update_dpp(0, __float_as_int(v), CTRL, 0xF, 0xF, false));
}

__device__ __forceinline__ float rsum16(float v) {
    v += dpp_add<0x121>(v);
    v += dpp_add<0x122>(v);
    v += dpp_add<0x124>(v);
    v += dpp_add<0x128>(v);
    return v;
}

__device__ __forceinline__ float rsum8(float v) {
    v += dpp_add<0xB1>(v);   // quad_perm xor1
    v += dpp_add<0x4E>(v);   // quad_perm xor2
    v += dpp_add<0x141>(v);  // row_half_mirror
    return v;
}

__device__ __forceinline__ float tanh_fast(float x) {
    float ex = __expf(fminf(2.f * x, 30.f));
    return (ex - 1.f) * RCPF(ex + 1.f);
}

// ---- fused pass 1: [0,EB) count | [EB,EB+PG) entity tables + EH | rest rel ----
__global__ __launch_bounds__(256) void k_pass1(
    const int*    __restrict__ head,
    const float4* __restrict__ ent,
    const float4* __restrict__ rel,
    int*     __restrict__ C,
    float2*  __restrict__ Th1,
    float2*  __restrict__ Tt1,
    float2*  __restrict__ RelC1,
    float2*  __restrict__ RelC2,
    __half2* __restrict__ EH2,     // [N*32] half2 view of fp16 embeddings
    __half2* __restrict__ RelH2,   // [NR*32]
    float ILAM2, int E, int N, int NR, int EB, int PG)
{
    int b = (int)blockIdx.x;
    if (b < EB) {
        int i = b * 256 + (int)threadIdx.x;
        if (i < E) atomicAdd(&C[head[i]], 1);
    } else if (b < EB + PG) {
        int gid = ((b - EB) * 256 + (int)threadIdx.x) >> 4;
        int g   = (int)threadIdx.x & 15;
        if (gid >= N) return;
        float4 v = ent[(size_t)gid * 16 + g];
        EH2[(size_t)gid * 32 + 2 * g]     = __floats2half2_rn(v.x, v.y);
        EH2[(size_t)gid * 32 + 2 * g + 1] = __floats2half2_rn(v.z, v.w);
        float n2 = rsum16(v.x * v.x + v.y * v.y + v.z * v.z + v.w * v.w);
        if (g == 0) {
            float nh     = fmaxf(SQRTF(fmaxf(n2, 0.f)), MIN_NORM);
            float inv_nh = RCPF(nh);
            float th     = tanh_fast(nh);
            Th1[gid] = make_float2(th * inv_nh, th * th);
            Tt1[gid] = make_float2(nh, inv_nh);
        }
    } else {
        int gid = ((b - EB - PG) * 256 + (int)threadIdx.x) >> 4;
        int g   = (int)threadIdx.x & 15;
        if (gid >= NR) return;
        float4 v = rel[(size_t)gid * 16 + g];
        RelH2[(size_t)gid * 32 + 2 * g]     = __floats2half2_rn(v.x, v.y);
        RelH2[(size_t)gid * 32 + 2 * g + 1] = __floats2half2_rn(v.z, v.w);
        float n2 = rsum16(v.x * v.x + v.y * v.y + v.z * v.z + v.w * v.w);
        if (g == 0) {
            float nr = fmaxf(SQRTF(n2), MIN_NORM);
            float inv_nr = RCPF(nr);
            RelC1[gid] = make_float2(nr, inv_nr);
            float thr2 = tanh_fast(ILAM2 * nr);
            RelC2[gid] = make_float2(thr2 * inv_nr, thr2 * thr2);
        }
    }
}

// ---- scan1: per-block inclusive scan C -> T, block sums -> BS, + degree hist ----
__global__ __launch_bounds__(256) void k_scan1(const int* __restrict__ C,
                                               int* __restrict__ T,
                                               int* __restrict__ BS,
                                               int* __restrict__ DH, int N) {
    __shared__ int lds[256];
    __shared__ int lh[64];
    if (threadIdx.x < 64) lh[threadIdx.x] = 0;
    int i = blockIdx.x * 256 + (int)threadIdx.x;
    int v = (i < N) ? C[i] : 0;
    lds[threadIdx.x] = v;
    __syncthreads();
    for (int off = 1; off < 256; off <<= 1) {
        int add = (threadIdx.x >= (unsigned)off) ? lds[threadIdx.x - off] : 0;
        __syncthreads();
        lds[threadIdx.x] += add;
        __syncthreads();
    }
    if (i < N) {
        T[i] = lds[threadIdx.x];
        int bd = 63 - min(v, 63);
        atomicAdd(&lh[bd], 1);
    }
    if (threadIdx.x == 255) BS[blockIdx.x] = lds[255];
    __syncthreads();
    if (threadIdx.x < 64 && lh[threadIdx.x] > 0)
        atomicAdd(&DH[threadIdx.x], lh[threadIdx.x]);
}

// ---- scan2: block 0 scans BS[nb]; block 1 scans DH->DB ----
__global__ __launch_bounds__(1024) void k_scan2(int* __restrict__ BS,
                                                const int* __restrict__ DH,
                                                int* __restrict__ DB, int nb) {
    if (blockIdx.x == 0) {
        __shared__ int lds[1024];
        int v = ((int)threadIdx.x < nb) ? BS[threadIdx.x] : 0;
        lds[threadIdx.x] = v;
        __syncthreads();
        for (int off = 1; off < 1024; off <<= 1) {
            int add = (threadIdx.x >= (unsigned)off) ? lds[threadIdx.x - off] : 0;
            __syncthreads();
            lds[threadIdx.x] += add;
            __syncthreads();
        }
        if ((int)threadIdx.x < nb) BS[threadIdx.x] = lds[threadIdx.x] - v;
    } else {
        __shared__ int lds[64];
        if (threadIdx.x >= 64) return;
        int t = (int)threadIdx.x;
        int v = DH[t];
        lds[t] = v;
        __syncthreads();
        for (int off = 1; off < 64; off <<= 1) {
            int add = (t >= off) ? lds[t - off] : 0;
            __syncthreads();
            lds[t] += add;
            __syncthreads();
        }
        DB[t] = lds[t] - v;
    }
}

// ---- scan3: ordered offsets OC={beg,cnt}, P=beg ----
__global__ __launch_bounds__(256) void k_scan3(const int* __restrict__ C,
                                               const int* __restrict__ T,
                                               const int* __restrict__ BS,
                                               int2* __restrict__ OC,
                                               int* __restrict__ P, int N) {
    int i = blockIdx.x * 256 + (int)threadIdx.x;
    if (i < N) {
        int c = C[i];
        int beg = T[i] - c + BS[blockIdx.x];
        OC[i] = make_int2(beg, c);
        P[i] = beg;
    }
}

// ---- fused pass 2: [0,NB) perm dscatter | [NB,..) region-routed edge scatter ----
__global__ __launch_bounds__(256) void k_pass2(
    const int* __restrict__ C,
    int*       __restrict__ DB,
    int*       __restrict__ perm,
    const int* __restrict__ head,
    const int* __restrict__ tail,
    const int* __restrict__ etype,
    int*       __restrict__ P,
    int*       __restrict__ rec,
    int N, int E, int NB, int SLICES)
{
    int b = (int)blockIdx.x;
    if (b < NB) {
        __shared__ int lh[64];
        __shared__ int lbase[64];
        if (threadIdx.x < 64) lh[threadIdx.x] = 0;
        __syncthreads();
        int i = b * 256 + (int)threadIdx.x;
        int bd = -1, lr = 0;
        if (i < N) {
            bd = 63 - min(C[i], 63);
            lr = atomicAdd(&lh[bd], 1);
        }
        __syncthreads();
        if (threadIdx.x < 64 && lh[threadIdx.x] > 0)
            lbase[threadIdx.x] = atomicAdd(&DB[threadIdx.x], lh[threadIdx.x]);
        __syncthreads();
        if (bd >= 0) perm[lbase[bd] + lr] = i;
    } else {
        int region = b & 7;
        int slice  = (b - NB) >> 3;
        int rlo = (int)(((long long)region * N) >> 3);
        int rhi = (int)(((long long)(region + 1) * N) >> 3);
        int step = 256 * SLICES;
        for (int i = slice * 256 + (int)threadIdx.x; i < E; i += step) {
            int h = head[i];
            int t = tail[i];
            int et = etype[i];
            if (h >= rlo && h < rhi) {
                int pos = atomicAdd(&P[h], 1);
                rec[pos] = t | ((et - 1) << 20);
            }
        }
    }
}

// ---- hop kernel: 8-lane group per head; fp16 gathers; fused epilogue ----
// lane l owns dim pairs {2l+16k, 2l+16k+1}, k=0..3 (acc[2k],acc[2k+1])
template<bool HOP2>
__global__ __launch_bounds__(256) void rgat_hop_kernel(
    const __half2* __restrict__ e2,     // hop1: EH2; hop2: Ah2 (32 half2/row)
    const __half2* __restrict__ rel2,   // [NR*32]
    const float2*  __restrict__ Th1,
    const float2*  __restrict__ Tt1,
    const float2*  __restrict__ Tt2,
    const float2*  __restrict__ RelC1,
    const float2*  __restrict__ RelC2,
    const int*     __restrict__ rec,
    const int2*    __restrict__ OC,
    const int*     __restrict__ perm,
    const float2*  __restrict__ entf2,  // hop2 only
    float2*        __restrict__ outf2,  // hop2 only
    __half2*       __restrict__ Ah2w,   // hop1 only
    float2*        __restrict__ Tt2w,   // hop1 only
    float SCP2, float P2C, float ILAM2, int N)
{
    int tid  = blockIdx.x * 256 + (int)threadIdx.x;
    int slot = tid >> 3;
    int l    = (int)threadIdx.x & 7;
    bool act = slot < N;
    int h    = perm[act ? slot : 0];

    int2 oc = OC[h];
    int beg = act ? oc.x : 0;
    int end = act ? (oc.x + oc.y) : 0;

    const __half2* hrow = e2 + (size_t)h * 32 + l;
    float hv[8];
#pragma unroll
    for (int k = 0; k < 4; ++k) {
        float2 f = __half22float2(hrow[8 * k]);
        hv[2 * k] = f.x; hv[2 * k + 1] = f.y;
    }

    float scp, p2;
    if constexpr (HOP2) {
        scp = SCP2; p2 = P2C;
    } else {
        float2 th = Th1[h];
        scp = th.x; p2 = th.y;
    }
    float bet  = fmaxf(1.f - p2, MIN_NORM);
    float ilam = RCPF(bet);
    float bet2 = bet * bet;

    float acc[8];
#pragma unroll
    for (int k = 0; k < 8; ++k) acc[k] = 0.f;

    float tA[8], rA[8], tB[8], rB[8];
    float2 tvA, rvA, tvB, rvB;

    auto LD = [&](int i, float* T, float* R, float2& TV, float2& RV) {
        int rc = rec[i];
        int ti = rc & 0xFFFFF;
        int ri = rc >> 20;
        const __half2* tr = e2   + (size_t)ti * 32 + l;
        const __half2* rr = rel2 + (size_t)ri * 32 + l;
#pragma unroll
        for (int k = 0; k < 4; ++k) {
            float2 ft = __half22float2(tr[8 * k]);
            float2 fr = __half22float2(rr[8 * k]);
            T[2 * k] = ft.x; T[2 * k + 1] = ft.y;
            R[2 * k] = fr.x; R[2 * k + 1] = fr.y;
        }
        if constexpr (HOP2) { TV = Tt2[ti]; RV = RelC2[ri]; }
        else               { TV = Tt1[ti]; RV = RelC1[ri]; }
    };

    auto COMPUTE = [&](const float* t, const float* r, float2 tv, float2 rv) {
        float pht = 0.f, phr = 0.f, ptr_ = 0.f;
#pragma unroll
        for (int k = 0; k < 8; ++k) {
            pht  += hv[k] * t[k];
            phr  += hv[k] * r[k];
            ptr_ += t[k] * r[k];
        }
        float ht  = rsum8(pht);
        float hr  = rsum8(phr);
        float ttr = rsum8(ptr_);

        float sct, y2t, scr, y2r;
        if constexpr (HOP2) {
            sct = tv.x; y2t = tv.y;
            scr = rv.x; y2r = rv.y;
        } else {
            float tht = tanh_fast(ilam * tv.x);
            sct = tht * tv.y;  y2t = tht * tht;
            float thr_ = tanh_fast(ilam * rv.x);
            scr = thr_ * rv.y; y2r = thr_ * thr_;
        }

        float xyt = scp * sct * ht;
        float xyr = scp * scr * hr;

        float alt  = fmaf(2.f, xyt, 1.f + y2t);
        float dent = fmaxf(fmaf(p2, y2t, fmaf(2.f, xyt, 1.f)), MIN_NORM);
        float alr  = fmaf(2.f, xyr, 1.f + y2r);
        float denr = fmaxf(fmaf(p2, y2r, fmaf(2.f, xyr, 1.f)), MIN_NORM);
        float iS   = RCPF(dent * denr);
        float idt  = iS * denr;
        float idr  = iS * dent;

        float a2 = (alt * alt * p2 + 2.f * alt * bet * xyt + bet * bet * y2t) * idt * idt;
        float pa = fmaf(bet, xyt, alt * p2) * idt;
        float b2 = (alr * alr * p2 + 2.f * alr * bet * xyr + bet * bet * y2r) * idr * idr;
        float pb = fmaf(bet, xyr, alr * p2) * idr;

        float ytyr = sct * scr * ttr;
        float ab = (alt * alr * p2 + alt * bet * xyr + bet * alr * xyt + bet * bet * ytyr) * idt * idr;

        float am   = fmaf(2.f, ab, 1.f + b2);
        float bm   = 1.f - a2;
        float denm = fmaxf(fmaf(a2, b2, fmaf(2.f, ab, 1.f)), MIN_NORM);
        float idm  = RCPF(denm);
        float m2  = (am * am * a2 + 2.f * am * bm * ab + bm * bm * b2) * idm * idm;
        float pmv = fmaf(am, pa, bm * pb) * idm;

        const float maxn  = 1.f - 4e-3f;
        const float maxn2 = maxn * maxn;
        float irm = RSQF(fmaxf(m2, 1e-30f));
        float sc  = (m2 > maxn2) ? (maxn * irm) : 1.f;
        m2  *= sc * sc;
        pmv *= sc;

        float cs   = fmaf(-2.f, pmv, 1.f + m2);
        float dens = fmaxf(fmaf(p2, m2, fmaf(-2.f, pmv, 1.f)), MIN_NORM);
        float ids  = RCPF(dens);
        float s2  = fmaxf((cs * cs * p2 - 2.f * cs * bet * pmv + bet * bet * m2) * ids * ids, 1e-30f);
        float irs = RSQF(s2);
        float ns  = s2 * irs;
        float xa  = fminf(ns, 1.f - 1e-7f);
        float ath = 0.5f * __logf((1.f + xa) * RCPF(1.f - xa));
        float lgs = bet * ath * irs;

        float X  = am * idt;
        float Y  = bm * idr;
        float G  = idm * sc;
        float W  = lgs * ids;
        float WG = W * G;
        float Kt = WG * X * bet2 * sct;
        float Kr = WG * Y * bet2 * scr;
        float Z  = WG * bet * fmaf(X, alt, Y * alr);
        float Kh = scp * (Z - W * cs);

#pragma unroll
        for (int k = 0; k < 8; ++k)
            acc[k] += fmaxf(fmaf(Kh, hv[k], fmaf(Kt, t[k], Kr * r[k])), 0.f);
    };

    int i = beg;
    if (i < end) {
        LD(i, tA, rA, tvA, rvA);
        while (true) {
            if (i + 1 < end) LD(i + 1, tB, rB, tvB, rvB);
            COMPUTE(tA, rA, tvA, rvA);
            ++i;
            if (i >= end) break;
            if (i + 1 < end) LD(i + 1, tA, rA, tvA, rvA);
            COMPUTE(tB, rB, tvB, rvB);
            ++i;
            if (i >= end) break;
        }
    }

    if (!act) return;

    float pn = 0.f;
#pragma unroll
    for (int k = 0; k < 8; ++k) pn += acc[k] * acc[k];
    float n2 = rsum8(pn);
    float sn = SQRTF(n2);
    float inv = RCPF(fmaxf(sn, 1e-12f));

    if constexpr (HOP2) {
        const float2* en = entf2 + (size_t)h * 32 + l;
        float2*       dd = outf2 + (size_t)h * 32 + l;
#pragma unroll
        for (int k = 0; k < 4; ++k) {
            float2 e = en[8 * k];
            float2 o;
            o.x = fmaf(0.25f, e.x, fmaf(0.5f, hv[2 * k],     acc[2 * k]     * inv));
            o.y = fmaf(0.25f, e.y, fmaf(0.5f, hv[2 * k + 1], acc[2 * k + 1] * inv));
            dd[8 * k] = o;
        }
    } else {
        __half2* ad = Ah2w + (size_t)h * 32 + l;
#pragma unroll
        for (int k = 0; k < 4; ++k)
            ad[8 * k] = __floats2half2_rn(acc[2 * k] * inv, acc[2 * k + 1] * inv);
        if (l == 0) {
            float nv = sn * inv;
            float nt = fmaxf(nv, MIN_NORM);
            float tht2 = tanh_fast(ILAM2 * nt);
            Tt2w[h] = make_float2(tht2 * RCPF(nt), tht2 * tht2);
        }
    }
}

extern "C" void kernel_launch(void* const* d_in, const int* in_sizes, int n_in,
                              void* d_out, int out_size, void* d_ws, size_t ws_size,
                              hipStream_t stream)
{
    const float* ent   = (const float*)d_in[0];
    const float* rel   = (const float*)d_in[1];
    const int*   eidx  = (const int*)d_in[2];
    const int*   etype = (const int*)d_in[3];

    int E = in_sizes[3];
    int N = in_sizes[0] / 64;
    int NR = in_sizes[1] / 64;
    const int* head = eidx;
    const int* tail = eidx + E;

    double th1d = tanh(1.0);
    float SCP2  = (float)th1d;
    float P2C   = (float)(th1d * th1d);
    float ILAM2 = (float)(1.0 / (1.0 - th1d * th1d));

    // ws layout:
    // EH[N*64 half] | Ah[N*64 half] | RelH[NR*64 half] | rec[E] | OC[int2 N] | P[N]
    // | C[N] DH[64] (one memset) | T[N] | BS[1024] | DB[64] | perm[N]
    // | Th1,Tt1,Tt2[N f2] | RelC1,RelC2[NR f2]
    __half2* EH2   = (__half2*)d_ws;                       // 25.6 MB
    __half2* Ah2   = EH2 + (size_t)N * 32;                 // 25.6 MB
    __half2* RelH2 = Ah2 + (size_t)N * 32;                 // 4 KB
    int*     rec   = (int*)(RelH2 + (size_t)NR * 32);      // 4 MB
    int2*    OC    = (int2*)(rec + E);
    int*     P     = (int*)(OC + N);
    int*     C     = P + N;
    int*     DH    = C + N;
    int*     T     = DH + 64;
    int*     BS    = T + N;
    int*     DB    = BS + 1024;
    int*     perm  = DB + 64;
    float2*  Th1   = (float2*)(perm + N);
    float2*  Tt1   = Th1 + N;
    float2*  Tt2   = Tt1 + N;
    float2*  RelC1 = Tt2 + N;
    float2*  RelC2 = RelC1 + NR;

    int NB = (N + 255) / 256;
    int EB = (E + 255) / 256;
    int PG = (N * 16 + 255) / 256;
    int RG = (NR * 16 + 255) / 256;
    const int SLICES = 104;

    float* out = (float*)d_out;
    dim3 blk(256);
    int hopGrid = (N * 8 + 255) / 256;

    (void)hipMemsetAsync(C, 0, (size_t)(N + 64) * sizeof(int), stream);

    k_pass1<<<EB + PG + RG, blk, 0, stream>>>(
        head, (const float4*)ent, (const float4*)rel,
        C, Th1, Tt1, RelC1, RelC2, EH2, RelH2, ILAM2, E, N, NR, EB, PG);

    k_scan1<<<NB, blk, 0, stream>>>(C, T, BS, DH, N);
    k_scan2<<<2, 1024, 0, stream>>>(BS, DH, DB, NB);
    k_scan3<<<NB, blk, 0, stream>>>(C, T, BS, OC, P, N);

    k_pass2<<<NB + 8 * SLICES, blk, 0, stream>>>(
        C, DB, perm, head, tail, etype, P, rec, N, E, NB, SLICES);

    rgat_hop_kernel<false><<<hopGrid, blk, 0, stream>>>(
        EH2, RelH2, Th1, Tt1, Tt2, RelC1, RelC2, rec, OC, perm,
        nullptr, nullptr, Ah2, Tt2, SCP2, P2C, ILAM2, N);

    rgat_hop_kernel<true><<<hopGrid, blk, 0, stream>>>(
        Ah2, RelH2, Th1, Tt1, Tt2, RelC1, RelC2, rec, OC, perm,
        (const float2*)ent, (float2*)out, nullptr, nullptr, SCP2, P2C, ILAM2, N);
}